// Round 6
// baseline (924.582 us; speedup 1.0000x reference)
//
#include <hip/hip_runtime.h>

#define NN 8192
#define DD 256
#define TOPK 32
#define SSTRIP 32   // score kernel: column strips
#define SW 256      // cols per strip

typedef __attribute__((ext_vector_type(8))) short short8v;
typedef __attribute__((ext_vector_type(4))) float floatx4;

__device__ __forceinline__ unsigned short f2bf(float f) {
  union { float f; unsigned int u; } x;
  x.f = f;
  unsigned int r = x.u + 0x7FFFu + ((x.u >> 16) & 1u);
  return (unsigned short)(r >> 16);
}
__device__ __forceinline__ unsigned short f2h(float f) {
  _Float16 h = (_Float16)f;
  return __builtin_bit_cast(unsigned short, h);
}
__device__ __forceinline__ float h2f(unsigned short u) {
  return (float)__builtin_bit_cast(_Float16, u);
}
// monotone 16-bit key for fp16: a<b (fp16) <=> key(a)<key(b) (uint16)
__device__ __forceinline__ unsigned int hkey(unsigned int u) {
  return (u & 0x8000u) ? ((~u) & 0xFFFFu) : (u | 0x8000u);
}
// Fragment-contiguous tile layout for MFMA operands (qb/kb):
// 16-row x 256-k panel stored as [kbi][l16][quad][8 elems] (4096 shorts).
// A wave's fragment load (l16, quad varying) is then 1KB CONTIGUOUS.
__device__ __forceinline__ size_t tile_off(int row, int j) {
  return ((size_t)(row >> 4) * 4096) + (size_t)(((j >> 5) * 512) +
         ((row & 15) * 32) + (((j >> 3) & 3) * 8) + (j & 7));
}

// ---------------------------------------------------------------------------
// Kernel 0: bf16 conversions. xb = bf16(x); wqkvb = bf16([Wq;Wk;Wv]);
// wgb = bf16(Wg). One float4 group per thread.
// ---------------------------------------------------------------------------
__global__ __launch_bounds__(256) void conv_kernel(
    const float* __restrict__ x,
    const float* __restrict__ Wq, const float* __restrict__ Wk,
    const float* __restrict__ Wv, const float* __restrict__ Wg,
    unsigned short* __restrict__ xb, unsigned short* __restrict__ wqkvb,
    unsigned short* __restrict__ wgb) {
  int g = blockIdx.x * 256 + threadIdx.x;   // float4 group id
  const float* src;
  unsigned short* dst;
  int e;
  if (g < 524288) {                 // x: 2097152 elems
    e = g * 4; src = x + e; dst = xb + e;
  } else if (g < 524288 + 49152) {  // Wq|Wk|Wv: 3 x 65536
    int e2 = (g - 524288) * 4;
    int which = e2 >> 16;
    int off = e2 & 65535;
    src = ((which == 0) ? Wq : (which == 1) ? Wk : Wv) + off;
    dst = wqkvb + which * 65536 + off;
  } else {                          // Wg: 131072
    int e3 = (g - 524288 - 49152) * 4;
    src = Wg + e3; dst = wgb + e3;
  }
  float4 f4 = *(const float4*)src;
  dst[0] = f2bf(f4.x); dst[1] = f2bf(f4.y);
  dst[2] = f2bf(f4.z); dst[3] = f2bf(f4.w);
}

// ---------------------------------------------------------------------------
// Kernel 0b: clog = fp16(log(clip(causal,1e-6))), stored in the UPPER 16KB of
// each 32KB weights row (lower 16KB will hold fp16 scores). Pure stream:
// 256MB read + 128MB write. Removes 16 v_log_f32/lane/iter from score and
// halves its cold HBM read.
// ---------------------------------------------------------------------------
__global__ __launch_bounds__(256) void clog_kernel(
    const float* __restrict__ causal, float* __restrict__ weights) {
  size_t g = (size_t)blockIdx.x * 256 + threadIdx.x;   // float4 id (16M total)
  size_t e = g * 4;
  int row = (int)(e >> 13);
  int col = (int)(e & 8191);
  float4 c = *(const float4*)(causal + e);
  unsigned int lo = (unsigned int)f2h(__logf(fmaxf(c.x, 1e-6f))) |
                    ((unsigned int)f2h(__logf(fmaxf(c.y, 1e-6f))) << 16);
  unsigned int hi = (unsigned int)f2h(__logf(fmaxf(c.z, 1e-6f))) |
                    ((unsigned int)f2h(__logf(fmaxf(c.w, 1e-6f))) << 16);
  unsigned short* crow = (unsigned short*)(weights + (size_t)row * NN + 4096);
  *(uint2*)(crow + col) = make_uint2(lo, hi);
}

// ---------------------------------------------------------------------------
// Kernel 1: q,k,v = x @ W.T + b via bf16 MFMA. q scaled by 1/16 (folded for
// scores). grid (6, 64, 4). q stored in fragment-contiguous tiles; k stored
// with the COLUMN-PAIRING permutation: stored slot s = (t&1)*16 + (t&31)/2
// within each 32-token group, so score's (ch,l16) fragment maps to actual
// token cb + 2*l16 + ch -> lane's two bias values are ADJACENT columns and
// the fp16 score row comes out in natural column order.
// ---------------------------------------------------------------------------
__global__ __launch_bounds__(256) void qkv_kernel(
    const unsigned short* __restrict__ xb,
    const unsigned short* __restrict__ wqkvb,
    const float* __restrict__ bq, const float* __restrict__ bk,
    const float* __restrict__ bvb,
    unsigned short* __restrict__ qb, unsigned short* __restrict__ kb,
    float* __restrict__ v) {
  int tid = threadIdx.x;
  int w = tid >> 6, lane = tid & 63;
  int quad = lane >> 4, l16 = lane & 15;
  int rb = blockIdx.y * 128;
  int cs = blockIdx.x * 128;   // 0..767 in steps of 128 (never crosses 256-bnd)
  int cb = cs + blockIdx.z * 32;

  short8v afrag[2][8];
#pragma unroll
  for (int rh = 0; rh < 2; rh++)
#pragma unroll
    for (int kbi = 0; kbi < 8; kbi++) {
      int row = rb + w * 32 + rh * 16 + l16;
      afrag[rh][kbi] =
          *(const short8v*)(xb + (size_t)row * 256 + kbi * 32 + quad * 8);
    }

  floatx4 zero4 = {0.0f, 0.0f, 0.0f, 0.0f};
  floatx4 acc[2][2];
  acc[0][0] = zero4; acc[0][1] = zero4; acc[1][0] = zero4; acc[1][1] = zero4;
#pragma unroll
  for (int kbi = 0; kbi < 8; kbi++) {
    short8v b0 = *(const short8v*)(wqkvb + (size_t)(cb + l16) * 256 + kbi * 32 + quad * 8);
    short8v b1 = *(const short8v*)(wqkvb + (size_t)(cb + 16 + l16) * 256 + kbi * 32 + quad * 8);
    acc[0][0] = __builtin_amdgcn_mfma_f32_16x16x32_bf16(afrag[0][kbi], b0, acc[0][0], 0, 0, 0);
    acc[0][1] = __builtin_amdgcn_mfma_f32_16x16x32_bf16(afrag[0][kbi], b1, acc[0][1], 0, 0, 0);
    acc[1][0] = __builtin_amdgcn_mfma_f32_16x16x32_bf16(afrag[1][kbi], b0, acc[1][0], 0, 0, 0);
    acc[1][1] = __builtin_amdgcn_mfma_f32_16x16x32_bf16(afrag[1][kbi], b1, acc[1][1], 0, 0, 0);
  }
#pragma unroll
  for (int rh = 0; rh < 2; rh++)
#pragma unroll
    for (int ch = 0; ch < 2; ch++)
#pragma unroll
      for (int r = 0; r < 4; r++) {
        int row = rb + w * 32 + rh * 16 + quad * 4 + r;
        int col = cb + ch * 16 + l16;           // 0..767
        int which = col >> 8;
        int j = col & 255;
        const float* bias = (which == 0) ? bq : (which == 1) ? bk : bvb;
        float val = acc[rh][ch][r] + bias[j];
        if (which == 0) {
          qb[tile_off(row, j)] = f2bf(val * 0.0625f);  // /16 folds 1/sqrt(d)
        } else if (which == 1) {
          int S = (row & ~31) | ((row & 1) << 4) | ((row & 31) >> 1);
          kb[tile_off(S, j)] = f2bf(val);
        } else {
          v[(size_t)row * 256 + j] = val;
        }
      }
}

// ---------------------------------------------------------------------------
// Kernel 2: biased scores s = q@k^T (q pre-scaled) + clog, stored fp16 in the
// LOWER 16KB of each 32KB weights row, NATURAL column order (thanks to the kb
// column-pairing). clog read from the UPPER 16KB (one uint = 2 adjacent cols
// per lane). Issue order honors in-order vmcnt: kb loads + MFMA first, then
// NEXT-iteration clog loads issued last so they stay in flight across the
// whole following iteration; epilogue uses the previous prefetch (already
// drained for free by the MFMA waits).
// ---------------------------------------------------------------------------
__global__ __launch_bounds__(256) void score_kernel(
    const unsigned short* __restrict__ qb,
    const unsigned short* __restrict__ kb,
    float* __restrict__ weights) {
  int tid = threadIdx.x;
  int w = tid >> 6, lane = tid & 63;
  int quad = lane >> 4, l16 = lane & 15;
  int rb = blockIdx.y * 128;
  int cs = blockIdx.x * SW;
  int fragoff = l16 * 32 + quad * 8;   // lane offset within 1KB fragment slice

  short8v afrag[2][8];
#pragma unroll
  for (int rh = 0; rh < 2; rh++) {
    int gA = (rb + w * 32 + rh * 16) >> 4;   // row-group (rows are 16-aligned)
#pragma unroll
    for (int kbi = 0; kbi < 8; kbi++)
      afrag[rh][kbi] =
          *(const short8v*)(qb + (size_t)gA * 4096 + kbi * 512 + fragoff);
  }

  // clog row pointers for this lane's 8 output rows
  const unsigned short* crow[2][4];
#pragma unroll
  for (int rh = 0; rh < 2; rh++)
#pragma unroll
    for (int r = 0; r < 4; r++) {
      int grow = rb + w * 32 + rh * 16 + quad * 4 + r;
      crow[rh][r] = (const unsigned short*)(weights + (size_t)grow * NN + 4096);
    }

  // prologue prefetch: clog for it=0 (2 adjacent cols per lane)
  unsigned int ccur[2][4];
#pragma unroll
  for (int rh = 0; rh < 2; rh++)
#pragma unroll
    for (int r = 0; r < 4; r++)
      ccur[rh][r] = *(const unsigned int*)(crow[rh][r] + cs + 2 * l16);

  floatx4 zero4 = {0.0f, 0.0f, 0.0f, 0.0f};
  for (int it = 0; it < SW / 32; it++) {
    int cb = cs + it * 32;
    const unsigned short* kbase = kb + (size_t)(cb >> 4) * 4096 + fragoff;

    floatx4 acc[2][2];
    acc[0][0] = zero4; acc[0][1] = zero4; acc[1][0] = zero4; acc[1][1] = zero4;
#pragma unroll
    for (int kbi = 0; kbi < 8; kbi++) {
      short8v b0 = *(const short8v*)(kbase + kbi * 512);          // slots cb..cb+15
      short8v b1 = *(const short8v*)(kbase + 4096 + kbi * 512);   // slots cb+16..cb+31
      acc[0][0] = __builtin_amdgcn_mfma_f32_16x16x32_bf16(afrag[0][kbi], b0, acc[0][0], 0, 0, 0);
      acc[0][1] = __builtin_amdgcn_mfma_f32_16x16x32_bf16(afrag[0][kbi], b1, acc[0][1], 0, 0, 0);
      acc[1][0] = __builtin_amdgcn_mfma_f32_16x16x32_bf16(afrag[1][kbi], b0, acc[1][0], 0, 0, 0);
      acc[1][1] = __builtin_amdgcn_mfma_f32_16x16x32_bf16(afrag[1][kbi], b1, acc[1][1], 0, 0, 0);
    }

    // prefetch NEXT iteration's clog (issued after kb loads -> stays
    // outstanding across the next iteration under in-order vmcnt)
    unsigned int cnxt[2][4];
    if (it + 1 < SW / 32) {
#pragma unroll
      for (int rh = 0; rh < 2; rh++)
#pragma unroll
        for (int r = 0; r < 4; r++)
          cnxt[rh][r] = *(const unsigned int*)(crow[rh][r] + cb + 32 + 2 * l16);
    }

    // epilogue: acc slot (ch,l16) = actual col cb + 2*l16 + ch
#pragma unroll
    for (int rh = 0; rh < 2; rh++)
#pragma unroll
      for (int r = 0; r < 4; r++) {
        int grow = rb + w * 32 + rh * 16 + quad * 4 + r;
        float l0 = h2f((unsigned short)(ccur[rh][r] & 0xFFFFu));
        float l1 = h2f((unsigned short)(ccur[rh][r] >> 16));
        float s0 = acc[rh][0][r] + l0;
        float s1 = acc[rh][1][r] + l1;
        unsigned int pk = (unsigned int)f2h(s0) | ((unsigned int)f2h(s1) << 16);
        unsigned short* sbrow = (unsigned short*)(weights + (size_t)grow * NN);
        *(unsigned int*)(sbrow + cb + l16 * 2) = pk;   // natural col order
      }
#pragma unroll
    for (int rh = 0; rh < 2; rh++)
#pragma unroll
      for (int r = 0; r < 4; r++) ccur[rh][r] = cnxt[rh][r];
  }
}

// ---------------------------------------------------------------------------
// Kernel 3a: per-row top-32 via register binary-search on fp16 keys + softmax.
// Scores are in NATURAL column order -> position == column. Writes COMPACT
// selC/selWt only. One block per row.
// ---------------------------------------------------------------------------
__global__ __launch_bounds__(256) void topk_kernel(
    const float* __restrict__ weights,
    int* __restrict__ selC, float* __restrict__ selWt) {
  __shared__ int part[72];        // binary-search partials (17 x 4)
  __shared__ int part2[8];        // scan partials
  __shared__ int selCol[TOPK];
  __shared__ float selSc[TOPK];

  int tid = threadIdx.x;
  int w = tid >> 6, lane = tid & 63;
  int row = blockIdx.x;
  const unsigned short* sb = (const unsigned short*)(weights + (size_t)row * NN);

  // load 32 fp16 scores (coalesced), build packed monotone keys
  uint4 raw[4];
#pragma unroll
  for (int c = 0; c < 4; c++)
    raw[c] = *(const uint4*)(sb + c * 2048 + tid * 8);
  unsigned int keys[16];
#pragma unroll
  for (int c = 0; c < 4; c++) {
    unsigned int rr[4] = {raw[c].x, raw[c].y, raw[c].z, raw[c].w};
#pragma unroll
    for (int u = 0; u < 4; u++) {
      unsigned int klo = hkey(rr[u] & 0xFFFFu);
      unsigned int khi = hkey(rr[u] >> 16);
      keys[c * 4 + u] = klo | (khi << 16);
    }
  }

  // binary search: smallest t with count(key > t) < TOPK  -> t = 32nd key
  int lo = 0, hi = 65535;
#pragma unroll 1
  for (int it = 0; it < 16; it++) {
    unsigned int mid = (unsigned int)((lo + hi) >> 1);
    int cnt = 0;
#pragma unroll
    for (int u = 0; u < 16; u++) {
      cnt += ((keys[u] & 0xFFFFu) > mid);
      cnt += ((keys[u] >> 16) > mid);
    }
#pragma unroll
    for (int off = 32; off >= 1; off >>= 1) cnt += __shfl_xor(cnt, off, 64);
    if (lane == 0) part[it * 4 + w] = cnt;
    __syncthreads();
    int tot = part[it * 4] + part[it * 4 + 1] + part[it * 4 + 2] + part[it * 4 + 3];
    if (lo < hi) { if (tot < TOPK) hi = (int)mid; else lo = (int)mid + 1; }
  }
  unsigned int K = (unsigned int)lo;

  // nGt = count(key > K)
  {
    int cnt = 0;
#pragma unroll
    for (int u = 0; u < 16; u++) {
      cnt += ((keys[u] & 0xFFFFu) > K);
      cnt += ((keys[u] >> 16) > K);
    }
#pragma unroll
    for (int off = 32; off >= 1; off >>= 1) cnt += __shfl_xor(cnt, off, 64);
    if (lane == 0) part[64 + w] = cnt;
  }
  __syncthreads();
  int nGt = part[64] + part[65] + part[66] + part[67];

  // per-thread counts + shuffle-based prefix scans for deterministic slots
  int cGt = 0, cEq = 0;
#pragma unroll
  for (int u = 0; u < 16; u++) {
    unsigned int a = keys[u] & 0xFFFFu, b = keys[u] >> 16;
    cGt += (a > K) + (b > K);
    cEq += (a == K) + (b == K);
  }
  int sGt = cGt;
#pragma unroll
  for (int off = 1; off < 64; off <<= 1) {
    int t = __shfl_up(sGt, off, 64);
    if (lane >= off) sGt += t;
  }
  if (lane == 63) part2[w] = sGt;
  int sEq = cEq;
#pragma unroll
  for (int off = 1; off < 64; off <<= 1) {
    int t = __shfl_up(sEq, off, 64);
    if (lane >= off) sEq += t;
  }
  if (lane == 63) part2[4 + w] = sEq;
  __syncthreads();
  int offGt = 0, offEq = 0;
  for (int j = 0; j < w; j++) { offGt += part2[j]; offEq += part2[4 + j]; }
  int posG = offGt + sGt - cGt;          // exclusive prefix of cGt
  int posT = nGt + offEq + sEq - cEq;    // tie slots after all strict-greater

  // collect selected entries (fixed order -> deterministic)
#pragma unroll
  for (int c = 0; c < 4; c++) {
    unsigned int rr[4] = {raw[c].x, raw[c].y, raw[c].z, raw[c].w};
#pragma unroll
    for (int e = 0; e < 8; e++) {
      unsigned int u16 = (e & 1) ? (rr[e >> 1] >> 16) : (rr[e >> 1] & 0xFFFFu);
      unsigned int k = hkey(u16);
      if (k > K || (k == K && posT < TOPK)) {
        int p = c * 2048 + tid * 8 + e;   // stored position == column (natural)
        int slot = (k > K) ? posG : posT;
        selCol[slot] = p;
        selSc[slot] = h2f((unsigned short)u16);
      }
      if (k > K) posG++;
      else if (k == K) posT++;
    }
  }
  __syncthreads();

  // softmax over the 32 selected (wave-parallel, deterministic), compact out
  if (tid < TOPK) {
    float s = selSc[tid];
    float m = s;
#pragma unroll
    for (int off = 16; off >= 1; off >>= 1) m = fmaxf(m, __shfl_xor(m, off, 64));
    float e = __expf(s - m);
    float Z = e;
#pragma unroll
    for (int off = 16; off >= 1; off >>= 1) Z += __shfl_xor(Z, off, 64);
    selC[(size_t)row * TOPK + tid] = selCol[tid];
    selWt[(size_t)row * TOPK + tid] = e / Z;
  }
}

// ---------------------------------------------------------------------------
// Kernel 3b: streaming dense-weights fill (register float4 zeros + scatter
// after barrier) + fused gather (fully unrolled: 32 independent loads in
// flight). One block per row, ~0.4 KB LDS -> 8 blocks/CU.
// ---------------------------------------------------------------------------
__global__ __launch_bounds__(256) void fill_gather_kernel(
    const int* __restrict__ selC, const float* __restrict__ selWt,
    float* __restrict__ weights, const float* __restrict__ v,
    float* __restrict__ fused, unsigned short* __restrict__ fb) {
  __shared__ int sc[TOPK];
  __shared__ float sw[TOPK];
  int tid = threadIdx.x;
  int row = blockIdx.x;
  if (tid < TOPK) {
    sc[tid] = selC[(size_t)row * TOPK + tid];
    sw[tid] = selWt[(size_t)row * TOPK + tid];
  }

  // zero the dense row straight from registers (overwrites the fp16 scores
  // AND the clog half, both already consumed)
  float* wrow = weights + (size_t)row * NN;
  float4 z4 = {0.0f, 0.0f, 0.0f, 0.0f};
#pragma unroll
  for (int c = 0; c < 8; c++) *(float4*)(wrow + c * 1024 + tid * 4) = z4;
  __syncthreads();   // zeros drained (vmcnt(0) before barrier) + sc/sw visible
  if (tid < TOPK) wrow[sc[tid]] = sw[tid];

  // fused[row][tid] = sum_i w_i * v[col_i][tid]; full unroll -> loads overlap
  float acc = 0.0f;
#pragma unroll
  for (int i = 0; i < TOPK; i++)
    acc += sw[i] * v[(size_t)sc[i] * DD + tid];
  fused[(size_t)row * DD + tid] = acc;
  fb[(size_t)row * DD + tid] = f2bf(acc);
}

// ---------------------------------------------------------------------------
// Kernel 4: gate = sigmoid([x|fused] @ Wg.T + bg); out = g*x + (1-g)*fused.
// bf16 MFMA, K=512 (xb then fb). grid (16, 64).
// ---------------------------------------------------------------------------
__global__ __launch_bounds__(256) void gate_kernel(
    const unsigned short* __restrict__ xb, const unsigned short* __restrict__ fb,
    const unsigned short* __restrict__ wgb, const float* __restrict__ bg,
    const float* __restrict__ x, const float* __restrict__ fused,
    float* __restrict__ out) {
  int tid = threadIdx.x;
  int w = tid >> 6, lane = tid & 63;
  int quad = lane >> 4, l16 = lane & 15;
  int rb = blockIdx.y * 128;
  int cs = blockIdx.x * 16;

  floatx4 acc[2];
  acc[0] = (floatx4){0.f, 0.f, 0.f, 0.f};
  acc[1] = (floatx4){0.f, 0.f, 0.f, 0.f};

#pragma unroll 1
  for (int kc = 0; kc < 2; kc++) {
    const unsigned short* asrc = kc ? fb : xb;
    short8v afrag[2][8];
#pragma unroll
    for (int rh = 0; rh < 2; rh++)
#pragma unroll
      for (int kbi = 0; kbi < 8; kbi++) {
        int row = rb + w * 32 + rh * 16 + l16;
        afrag[rh][kbi] =
            *(const short8v*)(asrc + (size_t)row * 256 + kbi * 32 + quad * 8);
      }
#pragma unroll
    for (int kbi = 0; kbi < 8; kbi++) {
      int col = cs + l16;
      short8v b = *(const short8v*)(wgb + (size_t)col * 512 + kc * 256 + kbi * 32 + quad * 8);
      acc[0] = __builtin_amdgcn_mfma_f32_16x16x32_bf16(afrag[0][kbi], b, acc[0], 0, 0, 0);
      acc[1] = __builtin_amdgcn_mfma_f32_16x16x32_bf16(afrag[1][kbi], b, acc[1], 0, 0, 0);
    }
  }
#pragma unroll
  for (int rh = 0; rh < 2; rh++)
#pragma unroll
    for (int r = 0; r < 4; r++) {
      int row = rb + w * 32 + rh * 16 + quad * 4 + r;
      int col = cs + l16;
      float t = acc[rh][r] + bg[col];
      float g = 1.0f / (1.0f + __expf(-t));
      size_t o = (size_t)row * 256 + col;
      out[o] = g * x[o] + (1.0f - g) * fused[o];
    }
}

// ---------------------------------------------------------------------------
extern "C" void kernel_launch(void* const* d_in, const int* in_sizes, int n_in,
                              void* d_out, int out_size, void* d_ws, size_t ws_size,
                              hipStream_t stream) {
  const float* x      = (const float*)d_in[0];
  const float* causal = (const float*)d_in[2];
  const float* Wq = (const float*)d_in[3];
  const float* bq = (const float*)d_in[4];
  const float* Wk = (const float*)d_in[5];
  const float* bk = (const float*)d_in[6];
  const float* Wv = (const float*)d_in[7];
  const float* bv = (const float*)d_in[8];
  const float* Wg = (const float*)d_in[9];
  const float* bg = (const float*)d_in[10];

  float* out = (float*)d_out;
  float* weights = out + (size_t)NN * DD;  // fp16 scores (low 16KB) + fp16 clog (high 16KB) per row

  char* ws = (char*)d_ws;
  unsigned short* xb    = (unsigned short*)(ws);                    // 4 MB
  unsigned short* wqkvb = (unsigned short*)(ws + (4u << 20));       // 384 KB
  unsigned short* wgb   = (unsigned short*)(ws + (4u << 20) + (512u << 10)); // 256 KB
  unsigned short* qb    = (unsigned short*)(ws + (5u << 20));       // 4 MB (tiled)
  unsigned short* kb    = (unsigned short*)(ws + (9u << 20));       // 4 MB (tiled, col-paired)
  float* v     = (float*)(ws + (13u << 20));                        // 8 MB
  float* fused = (float*)(ws + (21u << 20));                        // 8 MB
  unsigned short* fb = (unsigned short*)(ws + (29u << 20));         // 4 MB
  // q/k are dead after score_kernel -> reuse their space for compact top-k
  int*   selC  = (int*)(ws + (5u << 20));                           // 1 MB
  float* selWt = (float*)(ws + (9u << 20));                         // 1 MB

  conv_kernel<<<dim3(2368), 256, 0, stream>>>(x, Wq, Wk, Wv, Wg, xb, wqkvb, wgb);
  clog_kernel<<<dim3(65536), 256, 0, stream>>>(causal, weights);
  qkv_kernel<<<dim3(6, 64, 4), 256, 0, stream>>>(xb, wqkvb, bq, bk, bv, qb, kb, v);
  score_kernel<<<dim3(SSTRIP, 64), 256, 0, stream>>>(qb, kb, weights);
  topk_kernel<<<dim3(NN), 256, 0, stream>>>(weights, selC, selWt);
  fill_gather_kernel<<<dim3(NN), 256, 0, stream>>>(selC, selWt, weights, v, fused, fb);
  gate_kernel<<<dim3(16, 64), 256, 0, stream>>>(xb, fb, wgb, bg, x, fused, out);
}

// Round 7
// 885.807 us; speedup vs baseline: 1.0438x; 1.0438x over previous
//
#include <hip/hip_runtime.h>

#define NN 8192
#define DD 256
#define TOPK 32
#define SSTRIP 32   // score kernel: column strips
#define SW 256      // cols per strip

typedef __attribute__((ext_vector_type(8))) short short8v;
typedef __attribute__((ext_vector_type(4))) float floatx4;

__device__ __forceinline__ unsigned short f2bf(float f) {
  union { float f; unsigned int u; } x;
  x.f = f;
  unsigned int r = x.u + 0x7FFFu + ((x.u >> 16) & 1u);
  return (unsigned short)(r >> 16);
}
__device__ __forceinline__ unsigned short f2h(float f) {
  _Float16 h = (_Float16)f;
  return __builtin_bit_cast(unsigned short, h);
}
__device__ __forceinline__ float h2f(unsigned short u) {
  return (float)__builtin_bit_cast(_Float16, u);
}
// monotone 16-bit key for fp16: a<b (fp16) <=> key(a)<key(b) (uint16)
__device__ __forceinline__ unsigned int hkey(unsigned int u) {
  return (u & 0x8000u) ? ((~u) & 0xFFFFu) : (u | 0x8000u);
}
// Fragment-contiguous tile layout for MFMA operands (qb/kb):
// 16-row x 256-k panel stored as [kbi][l16][quad][8 elems] (4096 shorts).
// A wave's fragment load (l16, quad varying) is then 1KB CONTIGUOUS.
__device__ __forceinline__ size_t tile_off(int row, int j) {
  return ((size_t)(row >> 4) * 4096) + (size_t)(((j >> 5) * 512) +
         ((row & 15) * 32) + (((j >> 3) & 3) * 8) + (j & 7));
}

// ---------------------------------------------------------------------------
// Kernel 0: bf16 conversions. xb = bf16(x); wqkvb = bf16([Wq;Wk;Wv]);
// wgb = bf16(Wg). One float4 group per thread.
// ---------------------------------------------------------------------------
__global__ __launch_bounds__(256) void conv_kernel(
    const float* __restrict__ x,
    const float* __restrict__ Wq, const float* __restrict__ Wk,
    const float* __restrict__ Wv, const float* __restrict__ Wg,
    unsigned short* __restrict__ xb, unsigned short* __restrict__ wqkvb,
    unsigned short* __restrict__ wgb) {
  int g = blockIdx.x * 256 + threadIdx.x;   // float4 group id
  const float* src;
  unsigned short* dst;
  int e;
  if (g < 524288) {                 // x: 2097152 elems
    e = g * 4; src = x + e; dst = xb + e;
  } else if (g < 524288 + 49152) {  // Wq|Wk|Wv: 3 x 65536
    int e2 = (g - 524288) * 4;
    int which = e2 >> 16;
    int off = e2 & 65535;
    src = ((which == 0) ? Wq : (which == 1) ? Wk : Wv) + off;
    dst = wqkvb + which * 65536 + off;
  } else {                          // Wg: 131072
    int e3 = (g - 524288 - 49152) * 4;
    src = Wg + e3; dst = wgb + e3;
  }
  float4 f4 = *(const float4*)src;
  dst[0] = f2bf(f4.x); dst[1] = f2bf(f4.y);
  dst[2] = f2bf(f4.z); dst[3] = f2bf(f4.w);
}

// ---------------------------------------------------------------------------
// Kernel 1: q,k,v = x @ W.T + b via bf16 MFMA. q scaled by 1/16 (folded for
// scores). grid (6, 64, 4). q stored in fragment-contiguous tiles; k stored
// with the COLUMN-PAIRING permutation: stored slot s = (t&1)*16 + (t&31)/2
// within each 32-token group, so score's (ch,l16) fragment maps to actual
// token cb + 2*l16 + ch -> lane's two causal values are ADJACENT columns
// (one float2 load) and the fp16 score row comes out in natural col order.
// ---------------------------------------------------------------------------
__global__ __launch_bounds__(256) void qkv_kernel(
    const unsigned short* __restrict__ xb,
    const unsigned short* __restrict__ wqkvb,
    const float* __restrict__ bq, const float* __restrict__ bk,
    const float* __restrict__ bvb,
    unsigned short* __restrict__ qb, unsigned short* __restrict__ kb,
    float* __restrict__ v) {
  int tid = threadIdx.x;
  int w = tid >> 6, lane = tid & 63;
  int quad = lane >> 4, l16 = lane & 15;
  int rb = blockIdx.y * 128;
  int cs = blockIdx.x * 128;   // 0..767 in steps of 128 (never crosses 256-bnd)
  int cb = cs + blockIdx.z * 32;

  short8v afrag[2][8];
#pragma unroll
  for (int rh = 0; rh < 2; rh++)
#pragma unroll
    for (int kbi = 0; kbi < 8; kbi++) {
      int row = rb + w * 32 + rh * 16 + l16;
      afrag[rh][kbi] =
          *(const short8v*)(xb + (size_t)row * 256 + kbi * 32 + quad * 8);
    }

  floatx4 zero4 = {0.0f, 0.0f, 0.0f, 0.0f};
  floatx4 acc[2][2];
  acc[0][0] = zero4; acc[0][1] = zero4; acc[1][0] = zero4; acc[1][1] = zero4;
#pragma unroll
  for (int kbi = 0; kbi < 8; kbi++) {
    short8v b0 = *(const short8v*)(wqkvb + (size_t)(cb + l16) * 256 + kbi * 32 + quad * 8);
    short8v b1 = *(const short8v*)(wqkvb + (size_t)(cb + 16 + l16) * 256 + kbi * 32 + quad * 8);
    acc[0][0] = __builtin_amdgcn_mfma_f32_16x16x32_bf16(afrag[0][kbi], b0, acc[0][0], 0, 0, 0);
    acc[0][1] = __builtin_amdgcn_mfma_f32_16x16x32_bf16(afrag[0][kbi], b1, acc[0][1], 0, 0, 0);
    acc[1][0] = __builtin_amdgcn_mfma_f32_16x16x32_bf16(afrag[1][kbi], b0, acc[1][0], 0, 0, 0);
    acc[1][1] = __builtin_amdgcn_mfma_f32_16x16x32_bf16(afrag[1][kbi], b1, acc[1][1], 0, 0, 0);
  }
#pragma unroll
  for (int rh = 0; rh < 2; rh++)
#pragma unroll
    for (int ch = 0; ch < 2; ch++)
#pragma unroll
      for (int r = 0; r < 4; r++) {
        int row = rb + w * 32 + rh * 16 + quad * 4 + r;
        int col = cb + ch * 16 + l16;           // 0..767
        int which = col >> 8;
        int j = col & 255;
        const float* bias = (which == 0) ? bq : (which == 1) ? bk : bvb;
        float val = acc[rh][ch][r] + bias[j];
        if (which == 0) {
          qb[tile_off(row, j)] = f2bf(val * 0.0625f);  // /16 folds 1/sqrt(d)
        } else if (which == 1) {
          int S = (row & ~31) | ((row & 1) << 4) | ((row & 31) >> 1);
          kb[tile_off(S, j)] = f2bf(val);
        } else {
          v[(size_t)row * 256 + j] = val;
        }
      }
}

// ---------------------------------------------------------------------------
// Kernel 2: biased scores s = q@k^T (q pre-scaled) + log(clip(causal,1e-6)),
// stored fp16 in the first 16KB of each 32KB weights row, NATURAL col order.
// Issue order honors in-order vmcnt: kb loads + MFMA first, then the NEXT
// iteration's causal float2 loads issued last so they stay in flight across
// the whole following iteration; epilogue uses the previous prefetch (already
// drained for free by the MFMA waits). log computed in epilogue (VALU idle).
// ---------------------------------------------------------------------------
__global__ __launch_bounds__(256) void score_kernel(
    const unsigned short* __restrict__ qb,
    const unsigned short* __restrict__ kb,
    const float* __restrict__ causal,
    float* __restrict__ weights) {
  int tid = threadIdx.x;
  int w = tid >> 6, lane = tid & 63;
  int quad = lane >> 4, l16 = lane & 15;
  int rb = blockIdx.y * 128;
  int cs = blockIdx.x * SW;
  int fragoff = l16 * 32 + quad * 8;   // lane offset within 1KB fragment slice

  short8v afrag[2][8];
#pragma unroll
  for (int rh = 0; rh < 2; rh++) {
    int gA = (rb + w * 32 + rh * 16) >> 4;   // row-group (rows are 16-aligned)
#pragma unroll
    for (int kbi = 0; kbi < 8; kbi++)
      afrag[rh][kbi] =
          *(const short8v*)(qb + (size_t)gA * 4096 + kbi * 512 + fragoff);
  }

  // causal row pointers for this lane's 8 output rows
  const float* crow[2][4];
#pragma unroll
  for (int rh = 0; rh < 2; rh++)
#pragma unroll
    for (int r = 0; r < 4; r++) {
      int grow = rb + w * 32 + rh * 16 + quad * 4 + r;
      crow[rh][r] = causal + (size_t)grow * NN;
    }

  // prologue prefetch: causal for it=0 (2 adjacent cols per lane, 8B load)
  float2 ccur[2][4];
#pragma unroll
  for (int rh = 0; rh < 2; rh++)
#pragma unroll
    for (int r = 0; r < 4; r++)
      ccur[rh][r] = *(const float2*)(crow[rh][r] + cs + 2 * l16);

  floatx4 zero4 = {0.0f, 0.0f, 0.0f, 0.0f};
  for (int it = 0; it < SW / 32; it++) {
    int cb = cs + it * 32;
    const unsigned short* kbase = kb + (size_t)(cb >> 4) * 4096 + fragoff;

    floatx4 acc[2][2];
    acc[0][0] = zero4; acc[0][1] = zero4; acc[1][0] = zero4; acc[1][1] = zero4;
#pragma unroll
    for (int kbi = 0; kbi < 8; kbi++) {
      short8v b0 = *(const short8v*)(kbase + kbi * 512);          // slots cb..cb+15
      short8v b1 = *(const short8v*)(kbase + 4096 + kbi * 512);   // slots cb+16..cb+31
      acc[0][0] = __builtin_amdgcn_mfma_f32_16x16x32_bf16(afrag[0][kbi], b0, acc[0][0], 0, 0, 0);
      acc[0][1] = __builtin_amdgcn_mfma_f32_16x16x32_bf16(afrag[0][kbi], b1, acc[0][1], 0, 0, 0);
      acc[1][0] = __builtin_amdgcn_mfma_f32_16x16x32_bf16(afrag[1][kbi], b0, acc[1][0], 0, 0, 0);
      acc[1][1] = __builtin_amdgcn_mfma_f32_16x16x32_bf16(afrag[1][kbi], b1, acc[1][1], 0, 0, 0);
    }

    // prefetch NEXT iteration's causal (issued after kb loads -> stays
    // outstanding across the next iteration under in-order vmcnt)
    float2 cnxt[2][4];
    if (it + 1 < SW / 32) {
#pragma unroll
      for (int rh = 0; rh < 2; rh++)
#pragma unroll
        for (int r = 0; r < 4; r++)
          cnxt[rh][r] = *(const float2*)(crow[rh][r] + cb + 32 + 2 * l16);
    }

    // epilogue: acc slot (ch,l16) = actual col cb + 2*l16 + ch
#pragma unroll
    for (int rh = 0; rh < 2; rh++)
#pragma unroll
      for (int r = 0; r < 4; r++) {
        int grow = rb + w * 32 + rh * 16 + quad * 4 + r;
        float s0 = acc[rh][0][r] + __logf(fmaxf(ccur[rh][r].x, 1e-6f));
        float s1 = acc[rh][1][r] + __logf(fmaxf(ccur[rh][r].y, 1e-6f));
        unsigned int pk = (unsigned int)f2h(s0) | ((unsigned int)f2h(s1) << 16);
        unsigned short* sbrow = (unsigned short*)(weights + (size_t)grow * NN);
        *(unsigned int*)(sbrow + cb + l16 * 2) = pk;   // natural col order
      }
#pragma unroll
    for (int rh = 0; rh < 2; rh++)
#pragma unroll
      for (int r = 0; r < 4; r++) ccur[rh][r] = cnxt[rh][r];
  }
}

// ---------------------------------------------------------------------------
// Kernel 3a: per-row top-32 via register binary-search on fp16 keys + softmax.
// Scores are in NATURAL column order -> position == column. Writes COMPACT
// selC/selWt only. One block per row.
// ---------------------------------------------------------------------------
__global__ __launch_bounds__(256) void topk_kernel(
    const float* __restrict__ weights,
    int* __restrict__ selC, float* __restrict__ selWt) {
  __shared__ int part[72];        // binary-search partials (17 x 4)
  __shared__ int part2[8];        // scan partials
  __shared__ int selCol[TOPK];
  __shared__ float selSc[TOPK];

  int tid = threadIdx.x;
  int w = tid >> 6, lane = tid & 63;
  int row = blockIdx.x;
  const unsigned short* sb = (const unsigned short*)(weights + (size_t)row * NN);

  // load 32 fp16 scores (coalesced), build packed monotone keys
  uint4 raw[4];
#pragma unroll
  for (int c = 0; c < 4; c++)
    raw[c] = *(const uint4*)(sb + c * 2048 + tid * 8);
  unsigned int keys[16];
#pragma unroll
  for (int c = 0; c < 4; c++) {
    unsigned int rr[4] = {raw[c].x, raw[c].y, raw[c].z, raw[c].w};
#pragma unroll
    for (int u = 0; u < 4; u++) {
      unsigned int klo = hkey(rr[u] & 0xFFFFu);
      unsigned int khi = hkey(rr[u] >> 16);
      keys[c * 4 + u] = klo | (khi << 16);
    }
  }

  // binary search: smallest t with count(key > t) < TOPK  -> t = 32nd key
  int lo = 0, hi = 65535;
#pragma unroll 1
  for (int it = 0; it < 16; it++) {
    unsigned int mid = (unsigned int)((lo + hi) >> 1);
    int cnt = 0;
#pragma unroll
    for (int u = 0; u < 16; u++) {
      cnt += ((keys[u] & 0xFFFFu) > mid);
      cnt += ((keys[u] >> 16) > mid);
    }
#pragma unroll
    for (int off = 32; off >= 1; off >>= 1) cnt += __shfl_xor(cnt, off, 64);
    if (lane == 0) part[it * 4 + w] = cnt;
    __syncthreads();
    int tot = part[it * 4] + part[it * 4 + 1] + part[it * 4 + 2] + part[it * 4 + 3];
    if (lo < hi) { if (tot < TOPK) hi = (int)mid; else lo = (int)mid + 1; }
  }
  unsigned int K = (unsigned int)lo;

  // nGt = count(key > K)
  {
    int cnt = 0;
#pragma unroll
    for (int u = 0; u < 16; u++) {
      cnt += ((keys[u] & 0xFFFFu) > K);
      cnt += ((keys[u] >> 16) > K);
    }
#pragma unroll
    for (int off = 32; off >= 1; off >>= 1) cnt += __shfl_xor(cnt, off, 64);
    if (lane == 0) part[64 + w] = cnt;
  }
  __syncthreads();
  int nGt = part[64] + part[65] + part[66] + part[67];

  // per-thread counts + shuffle-based prefix scans for deterministic slots
  int cGt = 0, cEq = 0;
#pragma unroll
  for (int u = 0; u < 16; u++) {
    unsigned int a = keys[u] & 0xFFFFu, b = keys[u] >> 16;
    cGt += (a > K) + (b > K);
    cEq += (a == K) + (b == K);
  }
  int sGt = cGt;
#pragma unroll
  for (int off = 1; off < 64; off <<= 1) {
    int t = __shfl_up(sGt, off, 64);
    if (lane >= off) sGt += t;
  }
  if (lane == 63) part2[w] = sGt;
  int sEq = cEq;
#pragma unroll
  for (int off = 1; off < 64; off <<= 1) {
    int t = __shfl_up(sEq, off, 64);
    if (lane >= off) sEq += t;
  }
  if (lane == 63) part2[4 + w] = sEq;
  __syncthreads();
  int offGt = 0, offEq = 0;
  for (int j = 0; j < w; j++) { offGt += part2[j]; offEq += part2[4 + j]; }
  int posG = offGt + sGt - cGt;          // exclusive prefix of cGt
  int posT = nGt + offEq + sEq - cEq;    // tie slots after all strict-greater

  // collect selected entries (fixed order -> deterministic)
#pragma unroll
  for (int c = 0; c < 4; c++) {
    unsigned int rr[4] = {raw[c].x, raw[c].y, raw[c].z, raw[c].w};
#pragma unroll
    for (int e = 0; e < 8; e++) {
      unsigned int u16 = (e & 1) ? (rr[e >> 1] >> 16) : (rr[e >> 1] & 0xFFFFu);
      unsigned int k = hkey(u16);
      if (k > K || (k == K && posT < TOPK)) {
        int p = c * 2048 + tid * 8 + e;   // stored position == column (natural)
        int slot = (k > K) ? posG : posT;
        selCol[slot] = p;
        selSc[slot] = h2f((unsigned short)u16);
      }
      if (k > K) posG++;
      else if (k == K) posT++;
    }
  }
  __syncthreads();

  // softmax over the 32 selected (wave-parallel, deterministic), compact out
  if (tid < TOPK) {
    float s = selSc[tid];
    float m = s;
#pragma unroll
    for (int off = 16; off >= 1; off >>= 1) m = fmaxf(m, __shfl_xor(m, off, 64));
    float e = __expf(s - m);
    float Z = e;
#pragma unroll
    for (int off = 16; off >= 1; off >>= 1) Z += __shfl_xor(Z, off, 64);
    selC[(size_t)row * TOPK + tid] = selCol[tid];
    selWt[(size_t)row * TOPK + tid] = e / Z;
  }
}

// ---------------------------------------------------------------------------
// Kernel 3b: streaming dense-weights fill (register float4 zeros + scatter
// after barrier) + fused gather (fully unrolled: 32 independent loads in
// flight). One block per row, ~0.4 KB LDS -> 8 blocks/CU.
// ---------------------------------------------------------------------------
__global__ __launch_bounds__(256) void fill_gather_kernel(
    const int* __restrict__ selC, const float* __restrict__ selWt,
    float* __restrict__ weights, const float* __restrict__ v,
    float* __restrict__ fused, unsigned short* __restrict__ fb) {
  __shared__ int sc[TOPK];
  __shared__ float sw[TOPK];
  int tid = threadIdx.x;
  int row = blockIdx.x;
  if (tid < TOPK) {
    sc[tid] = selC[(size_t)row * TOPK + tid];
    sw[tid] = selWt[(size_t)row * TOPK + tid];
  }

  // zero the dense row straight from registers (overwrites the fp16 scores,
  // which topk_kernel has already consumed)
  float* wrow = weights + (size_t)row * NN;
  float4 z4 = {0.0f, 0.0f, 0.0f, 0.0f};
#pragma unroll
  for (int c = 0; c < 8; c++) *(float4*)(wrow + c * 1024 + tid * 4) = z4;
  __syncthreads();   // zeros drained (vmcnt(0) before barrier) + sc/sw visible
  if (tid < TOPK) wrow[sc[tid]] = sw[tid];

  // fused[row][tid] = sum_i w_i * v[col_i][tid]; full unroll -> loads overlap
  float acc = 0.0f;
#pragma unroll
  for (int i = 0; i < TOPK; i++)
    acc += sw[i] * v[(size_t)sc[i] * DD + tid];
  fused[(size_t)row * DD + tid] = acc;
  fb[(size_t)row * DD + tid] = f2bf(acc);
}

// ---------------------------------------------------------------------------
// Kernel 4: gate = sigmoid([x|fused] @ Wg.T + bg); out = g*x + (1-g)*fused.
// bf16 MFMA, K=512 (xb then fb). grid (16, 64).
// ---------------------------------------------------------------------------
__global__ __launch_bounds__(256) void gate_kernel(
    const unsigned short* __restrict__ xb, const unsigned short* __restrict__ fb,
    const unsigned short* __restrict__ wgb, const float* __restrict__ bg,
    const float* __restrict__ x, const float* __restrict__ fused,
    float* __restrict__ out) {
  int tid = threadIdx.x;
  int w = tid >> 6, lane = tid & 63;
  int quad = lane >> 4, l16 = lane & 15;
  int rb = blockIdx.y * 128;
  int cs = blockIdx.x * 16;

  floatx4 acc[2];
  acc[0] = (floatx4){0.f, 0.f, 0.f, 0.f};
  acc[1] = (floatx4){0.f, 0.f, 0.f, 0.f};

#pragma unroll 1
  for (int kc = 0; kc < 2; kc++) {
    const unsigned short* asrc = kc ? fb : xb;
    short8v afrag[2][8];
#pragma unroll
    for (int rh = 0; rh < 2; rh++)
#pragma unroll
      for (int kbi = 0; kbi < 8; kbi++) {
        int row = rb + w * 32 + rh * 16 + l16;
        afrag[rh][kbi] =
            *(const short8v*)(asrc + (size_t)row * 256 + kbi * 32 + quad * 8);
      }
#pragma unroll
    for (int kbi = 0; kbi < 8; kbi++) {
      int col = cs + l16;
      short8v b = *(const short8v*)(wgb + (size_t)col * 512 + kc * 256 + kbi * 32 + quad * 8);
      acc[0] = __builtin_amdgcn_mfma_f32_16x16x32_bf16(afrag[0][kbi], b, acc[0], 0, 0, 0);
      acc[1] = __builtin_amdgcn_mfma_f32_16x16x32_bf16(afrag[1][kbi], b, acc[1], 0, 0, 0);
    }
  }
#pragma unroll
  for (int rh = 0; rh < 2; rh++)
#pragma unroll
    for (int r = 0; r < 4; r++) {
      int row = rb + w * 32 + rh * 16 + quad * 4 + r;
      int col = cs + l16;
      float t = acc[rh][r] + bg[col];
      float g = 1.0f / (1.0f + __expf(-t));
      size_t o = (size_t)row * 256 + col;
      out[o] = g * x[o] + (1.0f - g) * fused[o];
    }
}

// ---------------------------------------------------------------------------
extern "C" void kernel_launch(void* const* d_in, const int* in_sizes, int n_in,
                              void* d_out, int out_size, void* d_ws, size_t ws_size,
                              hipStream_t stream) {
  const float* x      = (const float*)d_in[0];
  const float* causal = (const float*)d_in[2];
  const float* Wq = (const float*)d_in[3];
  const float* bq = (const float*)d_in[4];
  const float* Wk = (const float*)d_in[5];
  const float* bk = (const float*)d_in[6];
  const float* Wv = (const float*)d_in[7];
  const float* bv = (const float*)d_in[8];
  const float* Wg = (const float*)d_in[9];
  const float* bg = (const float*)d_in[10];

  float* out = (float*)d_out;
  float* weights = out + (size_t)NN * DD;  // fp16 score scratch lives in row head

  char* ws = (char*)d_ws;
  unsigned short* xb    = (unsigned short*)(ws);                    // 4 MB
  unsigned short* wqkvb = (unsigned short*)(ws + (4u << 20));       // 384 KB
  unsigned short* wgb   = (unsigned short*)(ws + (4u << 20) + (512u << 10)); // 256 KB
  unsigned short* qb    = (unsigned short*)(ws + (5u << 20));       // 4 MB (tiled)
  unsigned short* kb    = (unsigned short*)(ws + (9u << 20));       // 4 MB (tiled, col-paired)
  float* v     = (float*)(ws + (13u << 20));                        // 8 MB
  float* fused = (float*)(ws + (21u << 20));                        // 8 MB
  unsigned short* fb = (unsigned short*)(ws + (29u << 20));         // 4 MB
  // q/k are dead after score_kernel -> reuse their space for compact top-k
  int*   selC  = (int*)(ws + (5u << 20));                           // 1 MB
  float* selWt = (float*)(ws + (9u << 20));                         // 1 MB

  conv_kernel<<<dim3(2368), 256, 0, stream>>>(x, Wq, Wk, Wv, Wg, xb, wqkvb, wgb);
  qkv_kernel<<<dim3(6, 64, 4), 256, 0, stream>>>(xb, wqkvb, bq, bk, bv, qb, kb, v);
  score_kernel<<<dim3(SSTRIP, 64), 256, 0, stream>>>(qb, kb, causal, weights);
  topk_kernel<<<dim3(NN), 256, 0, stream>>>(weights, selC, selWt);
  fill_gather_kernel<<<dim3(NN), 256, 0, stream>>>(selC, selWt, weights, v, fused, fb);
  gate_kernel<<<dim3(16, 64), 256, 0, stream>>>(xb, fb, wgb, bg, x, fused, out);
}

// Round 8
// 849.127 us; speedup vs baseline: 1.0889x; 1.0432x over previous
//
#include <hip/hip_runtime.h>

#define NN 8192
#define DD 256
#define TOPK 32
#define SSTRIP 32   // score kernel: column strips
#define SW 256      // cols per strip
#define NIT (SW / 32)

typedef __attribute__((ext_vector_type(8))) short short8v;
typedef __attribute__((ext_vector_type(4))) float floatx4;

__device__ __forceinline__ unsigned short f2bf(float f) {
  union { float f; unsigned int u; } x;
  x.f = f;
  unsigned int r = x.u + 0x7FFFu + ((x.u >> 16) & 1u);
  return (unsigned short)(r >> 16);
}
__device__ __forceinline__ unsigned short f2h(float f) {
  _Float16 h = (_Float16)f;
  return __builtin_bit_cast(unsigned short, h);
}
__device__ __forceinline__ float h2f(unsigned short u) {
  return (float)__builtin_bit_cast(_Float16, u);
}
// monotone 16-bit key for fp16: a<b (fp16) <=> key(a)<key(b) (uint16)
__device__ __forceinline__ unsigned int hkey(unsigned int u) {
  return (u & 0x8000u) ? ((~u) & 0xFFFFu) : (u | 0x8000u);
}
// LANE-LINEAR fragment tile layout for MFMA operands (qb/kb):
// 16-row x 256-k panel = 4096 shorts, stored [kbi][lane][8] with
// lane = quad*16 + l16 (quad = k-subgroup, l16 = row within tile).
// A wave's fragment load is lane*16B CONTIGUOUS (global AND LDS-conflict-free).
__device__ __forceinline__ size_t tile_off(int row, int j) {
  return ((size_t)(row >> 4) * 4096) + (size_t)(((j >> 5) * 512) +
         (((j >> 3) & 3) * 128) + ((row & 15) * 8) + (j & 7));
}

// async global->LDS copy, 16B per lane, wave-uniform LDS base
#define ASYNC_CP16(gsrc, ldst)                                              \
  __builtin_amdgcn_global_load_lds(                                         \
      (__attribute__((address_space(1))) const void*)(gsrc),                \
      (__attribute__((address_space(3))) void*)(ldst), 16, 0, 0)

// ---------------------------------------------------------------------------
// Kernel 0: bf16 conversions. xb = bf16(x); wqkvb = bf16([Wq;Wk;Wv]);
// wgb = bf16(Wg). One float4 group per thread.
// ---------------------------------------------------------------------------
__global__ __launch_bounds__(256) void conv_kernel(
    const float* __restrict__ x,
    const float* __restrict__ Wq, const float* __restrict__ Wk,
    const float* __restrict__ Wv, const float* __restrict__ Wg,
    unsigned short* __restrict__ xb, unsigned short* __restrict__ wqkvb,
    unsigned short* __restrict__ wgb) {
  int g = blockIdx.x * 256 + threadIdx.x;   // float4 group id
  const float* src;
  unsigned short* dst;
  int e;
  if (g < 524288) {                 // x: 2097152 elems
    e = g * 4; src = x + e; dst = xb + e;
  } else if (g < 524288 + 49152) {  // Wq|Wk|Wv: 3 x 65536
    int e2 = (g - 524288) * 4;
    int which = e2 >> 16;
    int off = e2 & 65535;
    src = ((which == 0) ? Wq : (which == 1) ? Wk : Wv) + off;
    dst = wqkvb + which * 65536 + off;
  } else {                          // Wg: 131072
    int e3 = (g - 524288 - 49152) * 4;
    src = Wg + e3; dst = wgb + e3;
  }
  float4 f4 = *(const float4*)src;
  dst[0] = f2bf(f4.x); dst[1] = f2bf(f4.y);
  dst[2] = f2bf(f4.z); dst[3] = f2bf(f4.w);
}

// ---------------------------------------------------------------------------
// Kernel 1: q,k,v = x @ W.T + b via bf16 MFMA. q scaled by 1/16 (folded for
// scores). grid (6, 64, 4). q/k stored in lane-linear fragment tiles; k rows
// additionally COLUMN-PAIRED: stored slot s = (t&1)*16 + (t&31)/2 within each
// 32-token group, so score's (ch,l16) fragment maps to token cb + 2*l16 + ch
// -> lane's two causal values are ADJACENT (one float2 load) and the fp16
// score row comes out in natural column order.
// ---------------------------------------------------------------------------
__global__ __launch_bounds__(256) void qkv_kernel(
    const unsigned short* __restrict__ xb,
    const unsigned short* __restrict__ wqkvb,
    const float* __restrict__ bq, const float* __restrict__ bk,
    const float* __restrict__ bvb,
    unsigned short* __restrict__ qb, unsigned short* __restrict__ kb,
    float* __restrict__ v) {
  int tid = threadIdx.x;
  int w = tid >> 6, lane = tid & 63;
  int quad = lane >> 4, l16 = lane & 15;
  int rb = blockIdx.y * 128;
  int cs = blockIdx.x * 128;   // 0..767 in steps of 128 (never crosses 256-bnd)
  int cb = cs + blockIdx.z * 32;

  short8v afrag[2][8];
#pragma unroll
  for (int rh = 0; rh < 2; rh++)
#pragma unroll
    for (int kbi = 0; kbi < 8; kbi++) {
      int row = rb + w * 32 + rh * 16 + l16;
      afrag[rh][kbi] =
          *(const short8v*)(xb + (size_t)row * 256 + kbi * 32 + quad * 8);
    }

  floatx4 zero4 = {0.0f, 0.0f, 0.0f, 0.0f};
  floatx4 acc[2][2];
  acc[0][0] = zero4; acc[0][1] = zero4; acc[1][0] = zero4; acc[1][1] = zero4;
#pragma unroll
  for (int kbi = 0; kbi < 8; kbi++) {
    short8v b0 = *(const short8v*)(wqkvb + (size_t)(cb + l16) * 256 + kbi * 32 + quad * 8);
    short8v b1 = *(const short8v*)(wqkvb + (size_t)(cb + 16 + l16) * 256 + kbi * 32 + quad * 8);
    acc[0][0] = __builtin_amdgcn_mfma_f32_16x16x32_bf16(afrag[0][kbi], b0, acc[0][0], 0, 0, 0);
    acc[0][1] = __builtin_amdgcn_mfma_f32_16x16x32_bf16(afrag[0][kbi], b1, acc[0][1], 0, 0, 0);
    acc[1][0] = __builtin_amdgcn_mfma_f32_16x16x32_bf16(afrag[1][kbi], b0, acc[1][0], 0, 0, 0);
    acc[1][1] = __builtin_amdgcn_mfma_f32_16x16x32_bf16(afrag[1][kbi], b1, acc[1][1], 0, 0, 0);
  }
#pragma unroll
  for (int rh = 0; rh < 2; rh++)
#pragma unroll
    for (int ch = 0; ch < 2; ch++)
#pragma unroll
      for (int r = 0; r < 4; r++) {
        int row = rb + w * 32 + rh * 16 + quad * 4 + r;
        int col = cb + ch * 16 + l16;           // 0..767
        int which = col >> 8;
        int j = col & 255;
        const float* bias = (which == 0) ? bq : (which == 1) ? bk : bvb;
        float val = acc[rh][ch][r] + bias[j];
        if (which == 0) {
          qb[tile_off(row, j)] = f2bf(val * 0.0625f);  // /16 folds 1/sqrt(d)
        } else if (which == 1) {
          int S = (row & ~31) | ((row & 1) << 4) | ((row & 31) >> 1);
          kb[tile_off(S, j)] = f2bf(val);
        } else {
          v[(size_t)row * 256 + j] = val;
        }
      }
}

// ---------------------------------------------------------------------------
// Kernel 2: biased scores s = q@k^T (q pre-scaled) + log(clip(causal,1e-6)),
// fp16 into the first 16KB of each 32KB weights row, natural col order.
// kb is DOUBLE-BUFFERED through LDS via global_load_lds (zero VGPR staging):
// per iteration {causal loads (oldest in vmcnt) -> stage(it+1) -> ds_read +
// MFMA from buf[it] -> epilogue}; barrier at loop top drains staging that was
// issued a full compute phase earlier. Lane-linear tiles -> conflict-free
// ds_read_b128 and contiguous 16KB staging chunks.
// ---------------------------------------------------------------------------
__global__ __launch_bounds__(256) void score_kernel(
    const unsigned short* __restrict__ qb,
    const unsigned short* __restrict__ kb,
    const float* __restrict__ causal,
    float* __restrict__ weights) {
  __shared__ unsigned short sm[2][8192];   // 2 x 16KB kb slabs
  int tid = threadIdx.x;
  int w = tid >> 6, lane = tid & 63;
  int quad = lane >> 4, l16 = lane & 15;
  int rb = blockIdx.y * 128;
  int cs = blockIdx.x * SW;

  // A fragments: lane-linear tile read (contiguous 1KB per wave-load)
  short8v afrag[2][8];
#pragma unroll
  for (int rh = 0; rh < 2; rh++) {
    int gA = (rb + w * 32 + rh * 16) >> 4;
#pragma unroll
    for (int kbi = 0; kbi < 8; kbi++)
      afrag[rh][kbi] = *(const short8v*)(qb + (size_t)gA * 4096 + kbi * 512 +
                                         (size_t)lane * 8);
  }

  // causal row pointers for this lane's 8 output rows
  const float* crow[2][4];
#pragma unroll
  for (int rh = 0; rh < 2; rh++)
#pragma unroll
    for (int r = 0; r < 4; r++) {
      int grow = rb + w * 32 + rh * 16 + quad * 4 + r;
      crow[rh][r] = causal + (size_t)grow * NN;
    }

  // prologue: stage kb slab for it=0 into sm[0] (16KB, 4 calls/wave)
  {
    const unsigned short* g0 = kb + (size_t)(cs >> 4) * 4096;
#pragma unroll
    for (int c = 0; c < 4; c++) {
      int chunk = w * 4 + c;   // 0..15, wave-uniform
      ASYNC_CP16(g0 + chunk * 512 + lane * 8, &sm[0][chunk * 512]);
    }
  }

  floatx4 zero4 = {0.0f, 0.0f, 0.0f, 0.0f};
  for (int it = 0; it < NIT; it++) {
    __syncthreads();   // drains vmcnt -> sm[it&1] staging complete
    int cb = cs + it * 32;

    // causal loads FIRST (oldest in vmcnt queue -> epilogue's wait on these
    // does not drain the staging issued below)
    float2 ccur[2][4];
#pragma unroll
    for (int rh = 0; rh < 2; rh++)
#pragma unroll
      for (int r = 0; r < 4; r++)
        ccur[rh][r] = *(const float2*)(crow[rh][r] + cb + 2 * l16);

    // stage NEXT iteration's kb slab into the other buffer
    if (it + 1 < NIT) {
      const unsigned short* gn = kb + (size_t)((cb + 32) >> 4) * 4096;
      unsigned short* smn = &sm[(it + 1) & 1][0];
#pragma unroll
      for (int c = 0; c < 4; c++) {
        int chunk = w * 4 + c;
        ASYNC_CP16(gn + chunk * 512 + lane * 8, smn + chunk * 512);
      }
    }

    // compute from sm[it&1]: conflict-free lane-linear ds_read_b128
    const unsigned short* smb = &sm[it & 1][0];
    floatx4 acc[2][2];
    acc[0][0] = zero4; acc[0][1] = zero4; acc[1][0] = zero4; acc[1][1] = zero4;
#pragma unroll
    for (int kbi = 0; kbi < 8; kbi++) {
      short8v b0 = *(const short8v*)(smb + kbi * 512 + lane * 8);
      short8v b1 = *(const short8v*)(smb + 4096 + kbi * 512 + lane * 8);
      acc[0][0] = __builtin_amdgcn_mfma_f32_16x16x32_bf16(afrag[0][kbi], b0, acc[0][0], 0, 0, 0);
      acc[0][1] = __builtin_amdgcn_mfma_f32_16x16x32_bf16(afrag[0][kbi], b1, acc[0][1], 0, 0, 0);
      acc[1][0] = __builtin_amdgcn_mfma_f32_16x16x32_bf16(afrag[1][kbi], b0, acc[1][0], 0, 0, 0);
      acc[1][1] = __builtin_amdgcn_mfma_f32_16x16x32_bf16(afrag[1][kbi], b1, acc[1][1], 0, 0, 0);
    }

    // epilogue: acc slot (ch,l16) = actual col cb + 2*l16 + ch
#pragma unroll
    for (int rh = 0; rh < 2; rh++)
#pragma unroll
      for (int r = 0; r < 4; r++) {
        int grow = rb + w * 32 + rh * 16 + quad * 4 + r;
        float s0 = acc[rh][0][r] + __logf(fmaxf(ccur[rh][r].x, 1e-6f));
        float s1 = acc[rh][1][r] + __logf(fmaxf(ccur[rh][r].y, 1e-6f));
        unsigned int pk = (unsigned int)f2h(s0) | ((unsigned int)f2h(s1) << 16);
        unsigned short* sbrow = (unsigned short*)(weights + (size_t)grow * NN);
        *(unsigned int*)(sbrow + cb + l16 * 2) = pk;   // natural col order
      }
  }
}

// ---------------------------------------------------------------------------
// Kernel 3a: per-row top-32 via register binary-search on fp16 keys + softmax.
// Scores are in NATURAL column order -> position == column. Writes COMPACT
// selC/selWt only. One block per row.
// ---------------------------------------------------------------------------
__global__ __launch_bounds__(256) void topk_kernel(
    const float* __restrict__ weights,
    int* __restrict__ selC, float* __restrict__ selWt) {
  __shared__ int part[72];        // binary-search partials (17 x 4)
  __shared__ int part2[8];        // scan partials
  __shared__ int selCol[TOPK];
  __shared__ float selSc[TOPK];

  int tid = threadIdx.x;
  int w = tid >> 6, lane = tid & 63;
  int row = blockIdx.x;
  const unsigned short* sb = (const unsigned short*)(weights + (size_t)row * NN);

  // load 32 fp16 scores (coalesced), build packed monotone keys
  uint4 raw[4];
#pragma unroll
  for (int c = 0; c < 4; c++)
    raw[c] = *(const uint4*)(sb + c * 2048 + tid * 8);
  unsigned int keys[16];
#pragma unroll
  for (int c = 0; c < 4; c++) {
    unsigned int rr[4] = {raw[c].x, raw[c].y, raw[c].z, raw[c].w};
#pragma unroll
    for (int u = 0; u < 4; u++) {
      unsigned int klo = hkey(rr[u] & 0xFFFFu);
      unsigned int khi = hkey(rr[u] >> 16);
      keys[c * 4 + u] = klo | (khi << 16);
    }
  }

  // binary search: smallest t with count(key > t) < TOPK  -> t = 32nd key
  int lo = 0, hi = 65535;
#pragma unroll 1
  for (int it = 0; it < 16; it++) {
    unsigned int mid = (unsigned int)((lo + hi) >> 1);
    int cnt = 0;
#pragma unroll
    for (int u = 0; u < 16; u++) {
      cnt += ((keys[u] & 0xFFFFu) > mid);
      cnt += ((keys[u] >> 16) > mid);
    }
#pragma unroll
    for (int off = 32; off >= 1; off >>= 1) cnt += __shfl_xor(cnt, off, 64);
    if (lane == 0) part[it * 4 + w] = cnt;
    __syncthreads();
    int tot = part[it * 4] + part[it * 4 + 1] + part[it * 4 + 2] + part[it * 4 + 3];
    if (lo < hi) { if (tot < TOPK) hi = (int)mid; else lo = (int)mid + 1; }
  }
  unsigned int K = (unsigned int)lo;

  // nGt = count(key > K)
  {
    int cnt = 0;
#pragma unroll
    for (int u = 0; u < 16; u++) {
      cnt += ((keys[u] & 0xFFFFu) > K);
      cnt += ((keys[u] >> 16) > K);
    }
#pragma unroll
    for (int off = 32; off >= 1; off >>= 1) cnt += __shfl_xor(cnt, off, 64);
    if (lane == 0) part[64 + w] = cnt;
  }
  __syncthreads();
  int nGt = part[64] + part[65] + part[66] + part[67];

  // per-thread counts + shuffle-based prefix scans for deterministic slots
  int cGt = 0, cEq = 0;
#pragma unroll
  for (int u = 0; u < 16; u++) {
    unsigned int a = keys[u] & 0xFFFFu, b = keys[u] >> 16;
    cGt += (a > K) + (b > K);
    cEq += (a == K) + (b == K);
  }
  int sGt = cGt;
#pragma unroll
  for (int off = 1; off < 64; off <<= 1) {
    int t = __shfl_up(sGt, off, 64);
    if (lane >= off) sGt += t;
  }
  if (lane == 63) part2[w] = sGt;
  int sEq = cEq;
#pragma unroll
  for (int off = 1; off < 64; off <<= 1) {
    int t = __shfl_up(sEq, off, 64);
    if (lane >= off) sEq += t;
  }
  if (lane == 63) part2[4 + w] = sEq;
  __syncthreads();
  int offGt = 0, offEq = 0;
  for (int j = 0; j < w; j++) { offGt += part2[j]; offEq += part2[4 + j]; }
  int posG = offGt + sGt - cGt;          // exclusive prefix of cGt
  int posT = nGt + offEq + sEq - cEq;    // tie slots after all strict-greater

  // collect selected entries (fixed order -> deterministic)
#pragma unroll
  for (int c = 0; c < 4; c++) {
    unsigned int rr[4] = {raw[c].x, raw[c].y, raw[c].z, raw[c].w};
#pragma unroll
    for (int e = 0; e < 8; e++) {
      unsigned int u16 = (e & 1) ? (rr[e >> 1] >> 16) : (rr[e >> 1] & 0xFFFFu);
      unsigned int k = hkey(u16);
      if (k > K || (k == K && posT < TOPK)) {
        int p = c * 2048 + tid * 8 + e;   // stored position == column (natural)
        int slot = (k > K) ? posG : posT;
        selCol[slot] = p;
        selSc[slot] = h2f((unsigned short)u16);
      }
      if (k > K) posG++;
      else if (k == K) posT++;
    }
  }
  __syncthreads();

  // softmax over the 32 selected (wave-parallel, deterministic), compact out
  if (tid < TOPK) {
    float s = selSc[tid];
    float m = s;
#pragma unroll
    for (int off = 16; off >= 1; off >>= 1) m = fmaxf(m, __shfl_xor(m, off, 64));
    float e = __expf(s - m);
    float Z = e;
#pragma unroll
    for (int off = 16; off >= 1; off >>= 1) Z += __shfl_xor(Z, off, 64);
    selC[(size_t)row * TOPK + tid] = selCol[tid];
    selWt[(size_t)row * TOPK + tid] = e / Z;
  }
}

// ---------------------------------------------------------------------------
// Kernel 3b: streaming dense-weights fill (register float4 zeros + scatter
// after barrier) + fused gather (fully unrolled: 32 independent loads in
// flight). One block per row, ~0.4 KB LDS -> 8 blocks/CU.
// ---------------------------------------------------------------------------
__global__ __launch_bounds__(256) void fill_gather_kernel(
    const int* __restrict__ selC, const float* __restrict__ selWt,
    float* __restrict__ weights, const float* __restrict__ v,
    float* __restrict__ fused, unsigned short* __restrict__ fb) {
  __shared__ int sc[TOPK];
  __shared__ float sw[TOPK];
  int tid = threadIdx.x;
  int row = blockIdx.x;
  if (tid < TOPK) {
    sc[tid] = selC[(size_t)row * TOPK + tid];
    sw[tid] = selWt[(size_t)row * TOPK + tid];
  }

  // zero the dense row straight from registers (overwrites the fp16 scores,
  // which topk_kernel has already consumed)
  float* wrow = weights + (size_t)row * NN;
  float4 z4 = {0.0f, 0.0f, 0.0f, 0.0f};
#pragma unroll
  for (int c = 0; c < 8; c++) *(float4*)(wrow + c * 1024 + tid * 4) = z4;
  __syncthreads();   // zeros drained (vmcnt(0) before barrier) + sc/sw visible
  if (tid < TOPK) wrow[sc[tid]] = sw[tid];

  // fused[row][tid] = sum_i w_i * v[col_i][tid]; full unroll -> loads overlap
  float acc = 0.0f;
#pragma unroll
  for (int i = 0; i < TOPK; i++)
    acc += sw[i] * v[(size_t)sc[i] * DD + tid];
  fused[(size_t)row * DD + tid] = acc;
  fb[(size_t)row * DD + tid] = f2bf(acc);
}

// ---------------------------------------------------------------------------
// Kernel 4: gate = sigmoid([x|fused] @ Wg.T + bg); out = g*x + (1-g)*fused.
// bf16 MFMA, K=512 (xb then fb). grid (16, 64).
// ---------------------------------------------------------------------------
__global__ __launch_bounds__(256) void gate_kernel(
    const unsigned short* __restrict__ xb, const unsigned short* __restrict__ fb,
    const unsigned short* __restrict__ wgb, const float* __restrict__ bg,
    const float* __restrict__ x, const float* __restrict__ fused,
    float* __restrict__ out) {
  int tid = threadIdx.x;
  int w = tid >> 6, lane = tid & 63;
  int quad = lane >> 4, l16 = lane & 15;
  int rb = blockIdx.y * 128;
  int cs = blockIdx.x * 16;

  floatx4 acc[2];
  acc[0] = (floatx4){0.f, 0.f, 0.f, 0.f};
  acc[1] = (floatx4){0.f, 0.f, 0.f, 0.f};

#pragma unroll 1
  for (int kc = 0; kc < 2; kc++) {
    const unsigned short* asrc = kc ? fb : xb;
    short8v afrag[2][8];
#pragma unroll
    for (int rh = 0; rh < 2; rh++)
#pragma unroll
      for (int kbi = 0; kbi < 8; kbi++) {
        int row = rb + w * 32 + rh * 16 + l16;
        afrag[rh][kbi] =
            *(const short8v*)(asrc + (size_t)row * 256 + kbi * 32 + quad * 8);
      }
#pragma unroll
    for (int kbi = 0; kbi < 8; kbi++) {
      int col = cs + l16;
      short8v b = *(const short8v*)(wgb + (size_t)col * 512 + kc * 256 + kbi * 32 + quad * 8);
      acc[0] = __builtin_amdgcn_mfma_f32_16x16x32_bf16(afrag[0][kbi], b, acc[0], 0, 0, 0);
      acc[1] = __builtin_amdgcn_mfma_f32_16x16x32_bf16(afrag[1][kbi], b, acc[1], 0, 0, 0);
    }
  }
#pragma unroll
  for (int rh = 0; rh < 2; rh++)
#pragma unroll
    for (int r = 0; r < 4; r++) {
      int row = rb + w * 32 + rh * 16 + quad * 4 + r;
      int col = cs + l16;
      float t = acc[rh][r] + bg[col];
      float g = 1.0f / (1.0f + __expf(-t));
      size_t o = (size_t)row * 256 + col;
      out[o] = g * x[o] + (1.0f - g) * fused[o];
    }
}

// ---------------------------------------------------------------------------
extern "C" void kernel_launch(void* const* d_in, const int* in_sizes, int n_in,
                              void* d_out, int out_size, void* d_ws, size_t ws_size,
                              hipStream_t stream) {
  const float* x      = (const float*)d_in[0];
  const float* causal = (const float*)d_in[2];
  const float* Wq = (const float*)d_in[3];
  const float* bq = (const float*)d_in[4];
  const float* Wk = (const float*)d_in[5];
  const float* bk = (const float*)d_in[6];
  const float* Wv = (const float*)d_in[7];
  const float* bv = (const float*)d_in[8];
  const float* Wg = (const float*)d_in[9];
  const float* bg = (const float*)d_in[10];

  float* out = (float*)d_out;
  float* weights = out + (size_t)NN * DD;  // fp16 score scratch lives in row head

  char* ws = (char*)d_ws;
  unsigned short* xb    = (unsigned short*)(ws);                    // 4 MB
  unsigned short* wqkvb = (unsigned short*)(ws + (4u << 20));       // 384 KB
  unsigned short* wgb   = (unsigned short*)(ws + (4u << 20) + (512u << 10)); // 256 KB
  unsigned short* qb    = (unsigned short*)(ws + (5u << 20));       // 4 MB (tiled)
  unsigned short* kb    = (unsigned short*)(ws + (9u << 20));       // 4 MB (tiled, col-paired)
  float* v     = (float*)(ws + (13u << 20));                        // 8 MB
  float* fused = (float*)(ws + (21u << 20));                        // 8 MB
  unsigned short* fb = (unsigned short*)(ws + (29u << 20));         // 4 MB
  // q/k are dead after score_kernel -> reuse their space for compact top-k
  int*   selC  = (int*)(ws + (5u << 20));                           // 1 MB
  float* selWt = (float*)(ws + (9u << 20));                         // 1 MB

  conv_kernel<<<dim3(2368), 256, 0, stream>>>(x, Wq, Wk, Wv, Wg, xb, wqkvb, wgb);
  qkv_kernel<<<dim3(6, 64, 4), 256, 0, stream>>>(xb, wqkvb, bq, bk, bv, qb, kb, v);
  score_kernel<<<dim3(SSTRIP, 64), 256, 0, stream>>>(qb, kb, causal, weights);
  topk_kernel<<<dim3(NN), 256, 0, stream>>>(weights, selC, selWt);
  fill_gather_kernel<<<dim3(NN), 256, 0, stream>>>(selC, selWt, weights, v, fused, fb);
  gate_kernel<<<dim3(16, 64), 256, 0, stream>>>(xb, fb, wgb, bg, x, fused, out);
}

// Round 9
// 829.285 us; speedup vs baseline: 1.1149x; 1.0239x over previous
//
#include <hip/hip_runtime.h>

#define NN 8192
#define DD 256
#define TOPK 32
#define SSTRIP 32   // score kernel: column strips
#define SW 256      // cols per strip
#define NIT (SW / 32)

typedef __attribute__((ext_vector_type(8))) short short8v;
typedef __attribute__((ext_vector_type(4))) float floatx4;

__device__ __forceinline__ unsigned short f2bf(float f) {
  union { float f; unsigned int u; } x;
  x.f = f;
  unsigned int r = x.u + 0x7FFFu + ((x.u >> 16) & 1u);
  return (unsigned short)(r >> 16);
}
__device__ __forceinline__ unsigned short f2h(float f) {
  _Float16 h = (_Float16)f;
  return __builtin_bit_cast(unsigned short, h);
}
__device__ __forceinline__ float h2f(unsigned short u) {
  return (float)__builtin_bit_cast(_Float16, u);
}
// monotone 16-bit key for fp16: a<b (fp16) <=> key(a)<key(b) (uint16)
__device__ __forceinline__ unsigned int hkey(unsigned int u) {
  return (u & 0x8000u) ? ((~u) & 0xFFFFu) : (u | 0x8000u);
}
// LANE-LINEAR fragment tile layout for MFMA operands (K=256 panels):
// 16-row x 256-k panel = 4096 shorts, stored [kbi][quad][l16][8].
// A wave's fragment load (lane = quad*16+l16) is lane*16B CONTIGUOUS.
__device__ __forceinline__ size_t tile_off(int row, int j) {
  return ((size_t)(row >> 4) * 4096) + (size_t)(((j >> 5) * 512) +
         (((j >> 3) & 3) * 128) + ((row & 15) * 8) + (j & 7));
}
// same, K=512 panels (for Wg): 16 x 512 = 8192 shorts
__device__ __forceinline__ size_t tile_off512(int row, int j) {
  return ((size_t)(row >> 4) * 8192) + (size_t)(((j >> 5) * 512) +
         (((j >> 3) & 3) * 128) + ((row & 15) * 8) + (j & 7));
}

// async global->LDS copy, 16B per lane, wave-uniform LDS base
#define ASYNC_CP16(gsrc, ldst)                                              \
  __builtin_amdgcn_global_load_lds(                                         \
      (__attribute__((address_space(1))) const void*)(gsrc),                \
      (__attribute__((address_space(3))) void*)(ldst), 16, 0, 0)

// ---------------------------------------------------------------------------
// Kernel 0: bf16 conversions into LANE-LINEAR TILES. xb/wqkvb tiled K=256,
// wgb tiled K=512. One float4 group per thread (4 consecutive elems stay
// contiguous inside an 8-elem tile group).
// ---------------------------------------------------------------------------
__global__ __launch_bounds__(256) void conv_kernel(
    const float* __restrict__ x,
    const float* __restrict__ Wq, const float* __restrict__ Wk,
    const float* __restrict__ Wv, const float* __restrict__ Wg,
    unsigned short* __restrict__ xb, unsigned short* __restrict__ wqkvb,
    unsigned short* __restrict__ wgb) {
  int g = blockIdx.x * 256 + threadIdx.x;   // float4 group id
  const float* src;
  unsigned short* dst;
  size_t t;
  if (g < 524288) {                 // x: 2097152 elems, row-major [8192][256]
    int e = g * 4;
    src = x + e;
    dst = xb;
    t = tile_off(e >> 8, e & 255);
  } else if (g < 524288 + 49152) {  // Wq|Wk|Wv: 3 x 65536, [256][256]
    int e2 = (g - 524288) * 4;
    int which = e2 >> 16;
    int off = e2 & 65535;
    src = ((which == 0) ? Wq : (which == 1) ? Wk : Wv) + off;
    dst = wqkvb + which * 65536;
    t = tile_off(off >> 8, off & 255);
  } else {                          // Wg: 131072, [256][512]
    int e3 = (g - 524288 - 49152) * 4;
    src = Wg + e3;
    dst = wgb;
    t = tile_off512(e3 >> 9, e3 & 511);
  }
  float4 f4 = *(const float4*)src;
  dst[t + 0] = f2bf(f4.x); dst[t + 1] = f2bf(f4.y);
  dst[t + 2] = f2bf(f4.z); dst[t + 3] = f2bf(f4.w);
}

// ---------------------------------------------------------------------------
// Kernel 1: q,k,v = x @ W.T + b via bf16 MFMA. q scaled by 1/16 (folded for
// scores). grid (6, 64, 4). ALL fragment loads contiguous (lane-linear tiles).
// q/k written as tiles; k rows additionally COLUMN-PAIRED (stored slot
// s = (t&1)*16 + (t&31)/2) so score's (ch,l16) slot maps to token
// cb + 2*l16 + ch -> causal float2 loads + natural score col order.
// ---------------------------------------------------------------------------
__global__ __launch_bounds__(256) void qkv_kernel(
    const unsigned short* __restrict__ xb,
    const unsigned short* __restrict__ wqkvb,
    const float* __restrict__ bq, const float* __restrict__ bk,
    const float* __restrict__ bvb,
    unsigned short* __restrict__ qb, unsigned short* __restrict__ kb,
    float* __restrict__ v) {
  int tid = threadIdx.x;
  int w = tid >> 6, lane = tid & 63;
  int quad = lane >> 4, l16 = lane & 15;
  int rb = blockIdx.y * 128;
  int cs = blockIdx.x * 128;   // 0..767 in steps of 128 (never crosses 256-bnd)
  int cb = cs + blockIdx.z * 32;
  int which = cb >> 8;
  int cbl = cb & 255;          // col within the 256-col W panel

  short8v afrag[2][8];
#pragma unroll
  for (int rh = 0; rh < 2; rh++) {
    int gA = (rb + w * 32 + rh * 16) >> 4;
#pragma unroll
    for (int kbi = 0; kbi < 8; kbi++)
      afrag[rh][kbi] = *(const short8v*)(xb + (size_t)gA * 4096 + kbi * 512 +
                                         (size_t)lane * 8);
  }

  const unsigned short* wt = wqkvb + which * 65536 + (size_t)(cbl >> 4) * 4096;
  floatx4 zero4 = {0.0f, 0.0f, 0.0f, 0.0f};
  floatx4 acc[2][2];
  acc[0][0] = zero4; acc[0][1] = zero4; acc[1][0] = zero4; acc[1][1] = zero4;
#pragma unroll
  for (int kbi = 0; kbi < 8; kbi++) {
    short8v b0 = *(const short8v*)(wt + kbi * 512 + lane * 8);
    short8v b1 = *(const short8v*)(wt + 4096 + kbi * 512 + lane * 8);
    acc[0][0] = __builtin_amdgcn_mfma_f32_16x16x32_bf16(afrag[0][kbi], b0, acc[0][0], 0, 0, 0);
    acc[0][1] = __builtin_amdgcn_mfma_f32_16x16x32_bf16(afrag[0][kbi], b1, acc[0][1], 0, 0, 0);
    acc[1][0] = __builtin_amdgcn_mfma_f32_16x16x32_bf16(afrag[1][kbi], b0, acc[1][0], 0, 0, 0);
    acc[1][1] = __builtin_amdgcn_mfma_f32_16x16x32_bf16(afrag[1][kbi], b1, acc[1][1], 0, 0, 0);
  }
#pragma unroll
  for (int rh = 0; rh < 2; rh++)
#pragma unroll
    for (int ch = 0; ch < 2; ch++)
#pragma unroll
      for (int r = 0; r < 4; r++) {
        int row = rb + w * 32 + rh * 16 + quad * 4 + r;
        int col = cb + ch * 16 + l16;           // 0..767
        int j = col & 255;
        const float* bias = (which == 0) ? bq : (which == 1) ? bk : bvb;
        float val = acc[rh][ch][r] + bias[j];
        if (which == 0) {
          qb[tile_off(row, j)] = f2bf(val * 0.0625f);  // /16 folds 1/sqrt(d)
        } else if (which == 1) {
          int S = (row & ~31) | ((row & 1) << 4) | ((row & 31) >> 1);
          kb[tile_off(S, j)] = f2bf(val);
        } else {
          v[(size_t)row * 256 + j] = val;
        }
      }
}

// ---------------------------------------------------------------------------
// Kernel 2: biased scores s = q@k^T (q pre-scaled) + log(clip(causal,1e-6)),
// fp16 into the first 16KB of each 32KB weights row, natural col order.
// kb DOUBLE-BUFFERED through LDS via global_load_lds (zero VGPR staging).
// ---------------------------------------------------------------------------
__global__ __launch_bounds__(256) void score_kernel(
    const unsigned short* __restrict__ qb,
    const unsigned short* __restrict__ kb,
    const float* __restrict__ causal,
    float* __restrict__ weights) {
  __shared__ unsigned short sm[2][8192];   // 2 x 16KB kb slabs
  int tid = threadIdx.x;
  int w = tid >> 6, lane = tid & 63;
  int quad = lane >> 4, l16 = lane & 15;
  int rb = blockIdx.y * 128;
  int cs = blockIdx.x * SW;

  // A fragments: lane-linear tile read (contiguous 1KB per wave-load)
  short8v afrag[2][8];
#pragma unroll
  for (int rh = 0; rh < 2; rh++) {
    int gA = (rb + w * 32 + rh * 16) >> 4;
#pragma unroll
    for (int kbi = 0; kbi < 8; kbi++)
      afrag[rh][kbi] = *(const short8v*)(qb + (size_t)gA * 4096 + kbi * 512 +
                                         (size_t)lane * 8);
  }

  // causal row pointers for this lane's 8 output rows
  const float* crow[2][4];
#pragma unroll
  for (int rh = 0; rh < 2; rh++)
#pragma unroll
    for (int r = 0; r < 4; r++) {
      int grow = rb + w * 32 + rh * 16 + quad * 4 + r;
      crow[rh][r] = causal + (size_t)grow * NN;
    }

  // prologue: stage kb slab for it=0 into sm[0] (16KB, 4 calls/wave)
  {
    const unsigned short* g0 = kb + (size_t)(cs >> 4) * 4096;
#pragma unroll
    for (int c = 0; c < 4; c++) {
      int chunk = w * 4 + c;   // 0..15, wave-uniform
      ASYNC_CP16(g0 + chunk * 512 + lane * 8, &sm[0][chunk * 512]);
    }
  }

  floatx4 zero4 = {0.0f, 0.0f, 0.0f, 0.0f};
  for (int it = 0; it < NIT; it++) {
    __syncthreads();   // drains vmcnt -> sm[it&1] staging complete
    int cb = cs + it * 32;

    // causal loads FIRST (oldest in vmcnt queue -> epilogue's wait on these
    // does not drain the staging issued below)
    float2 ccur[2][4];
#pragma unroll
    for (int rh = 0; rh < 2; rh++)
#pragma unroll
      for (int r = 0; r < 4; r++)
        ccur[rh][r] = *(const float2*)(crow[rh][r] + cb + 2 * l16);

    // stage NEXT iteration's kb slab into the other buffer
    if (it + 1 < NIT) {
      const unsigned short* gn = kb + (size_t)((cb + 32) >> 4) * 4096;
      unsigned short* smn = &sm[(it + 1) & 1][0];
#pragma unroll
      for (int c = 0; c < 4; c++) {
        int chunk = w * 4 + c;
        ASYNC_CP16(gn + chunk * 512 + lane * 8, smn + chunk * 512);
      }
    }

    // compute from sm[it&1]: conflict-free lane-linear ds_read_b128
    const unsigned short* smb = &sm[it & 1][0];
    floatx4 acc[2][2];
    acc[0][0] = zero4; acc[0][1] = zero4; acc[1][0] = zero4; acc[1][1] = zero4;
#pragma unroll
    for (int kbi = 0; kbi < 8; kbi++) {
      short8v b0 = *(const short8v*)(smb + kbi * 512 + lane * 8);
      short8v b1 = *(const short8v*)(smb + 4096 + kbi * 512 + lane * 8);
      acc[0][0] = __builtin_amdgcn_mfma_f32_16x16x32_bf16(afrag[0][kbi], b0, acc[0][0], 0, 0, 0);
      acc[0][1] = __builtin_amdgcn_mfma_f32_16x16x32_bf16(afrag[0][kbi], b1, acc[0][1], 0, 0, 0);
      acc[1][0] = __builtin_amdgcn_mfma_f32_16x16x32_bf16(afrag[1][kbi], b0, acc[1][0], 0, 0, 0);
      acc[1][1] = __builtin_amdgcn_mfma_f32_16x16x32_bf16(afrag[1][kbi], b1, acc[1][1], 0, 0, 0);
    }

    // epilogue: acc slot (ch,l16) = actual col cb + 2*l16 + ch
#pragma unroll
    for (int rh = 0; rh < 2; rh++)
#pragma unroll
      for (int r = 0; r < 4; r++) {
        int grow = rb + w * 32 + rh * 16 + quad * 4 + r;
        float s0 = acc[rh][0][r] + __logf(fmaxf(ccur[rh][r].x, 1e-6f));
        float s1 = acc[rh][1][r] + __logf(fmaxf(ccur[rh][r].y, 1e-6f));
        unsigned int pk = (unsigned int)f2h(s0) | ((unsigned int)f2h(s1) << 16);
        unsigned short* sbrow = (unsigned short*)(weights + (size_t)grow * NN);
        *(unsigned int*)(sbrow + cb + l16 * 2) = pk;   // natural col order
      }
  }
}

// ---------------------------------------------------------------------------
// Kernel 3a: per-row top-32 via register binary-search on fp16 keys + softmax.
// Scores are in NATURAL column order -> position == column. Writes COMPACT
// selC/selWt only. One block per row.
// ---------------------------------------------------------------------------
__global__ __launch_bounds__(256) void topk_kernel(
    const float* __restrict__ weights,
    int* __restrict__ selC, float* __restrict__ selWt) {
  __shared__ int part[72];        // binary-search partials (17 x 4)
  __shared__ int part2[8];        // scan partials
  __shared__ int selCol[TOPK];
  __shared__ float selSc[TOPK];

  int tid = threadIdx.x;
  int w = tid >> 6, lane = tid & 63;
  int row = blockIdx.x;
  const unsigned short* sb = (const unsigned short*)(weights + (size_t)row * NN);

  // load 32 fp16 scores (coalesced), build packed monotone keys
  uint4 raw[4];
#pragma unroll
  for (int c = 0; c < 4; c++)
    raw[c] = *(const uint4*)(sb + c * 2048 + tid * 8);
  unsigned int keys[16];
#pragma unroll
  for (int c = 0; c < 4; c++) {
    unsigned int rr[4] = {raw[c].x, raw[c].y, raw[c].z, raw[c].w};
#pragma unroll
    for (int u = 0; u < 4; u++) {
      unsigned int klo = hkey(rr[u] & 0xFFFFu);
      unsigned int khi = hkey(rr[u] >> 16);
      keys[c * 4 + u] = klo | (khi << 16);
    }
  }

  // binary search: smallest t with count(key > t) < TOPK  -> t = 32nd key
  int lo = 0, hi = 65535;
#pragma unroll 1
  for (int it = 0; it < 16; it++) {
    unsigned int mid = (unsigned int)((lo + hi) >> 1);
    int cnt = 0;
#pragma unroll
    for (int u = 0; u < 16; u++) {
      cnt += ((keys[u] & 0xFFFFu) > mid);
      cnt += ((keys[u] >> 16) > mid);
    }
#pragma unroll
    for (int off = 32; off >= 1; off >>= 1) cnt += __shfl_xor(cnt, off, 64);
    if (lane == 0) part[it * 4 + w] = cnt;
    __syncthreads();
    int tot = part[it * 4] + part[it * 4 + 1] + part[it * 4 + 2] + part[it * 4 + 3];
    if (lo < hi) { if (tot < TOPK) hi = (int)mid; else lo = (int)mid + 1; }
  }
  unsigned int K = (unsigned int)lo;

  // nGt = count(key > K)
  {
    int cnt = 0;
#pragma unroll
    for (int u = 0; u < 16; u++) {
      cnt += ((keys[u] & 0xFFFFu) > K);
      cnt += ((keys[u] >> 16) > K);
    }
#pragma unroll
    for (int off = 32; off >= 1; off >>= 1) cnt += __shfl_xor(cnt, off, 64);
    if (lane == 0) part[64 + w] = cnt;
  }
  __syncthreads();
  int nGt = part[64] + part[65] + part[66] + part[67];

  // per-thread counts + shuffle-based prefix scans for deterministic slots
  int cGt = 0, cEq = 0;
#pragma unroll
  for (int u = 0; u < 16; u++) {
    unsigned int a = keys[u] & 0xFFFFu, b = keys[u] >> 16;
    cGt += (a > K) + (b > K);
    cEq += (a == K) + (b == K);
  }
  int sGt = cGt;
#pragma unroll
  for (int off = 1; off < 64; off <<= 1) {
    int t = __shfl_up(sGt, off, 64);
    if (lane >= off) sGt += t;
  }
  if (lane == 63) part2[w] = sGt;
  int sEq = cEq;
#pragma unroll
  for (int off = 1; off < 64; off <<= 1) {
    int t = __shfl_up(sEq, off, 64);
    if (lane >= off) sEq += t;
  }
  if (lane == 63) part2[4 + w] = sEq;
  __syncthreads();
  int offGt = 0, offEq = 0;
  for (int j = 0; j < w; j++) { offGt += part2[j]; offEq += part2[4 + j]; }
  int posG = offGt + sGt - cGt;          // exclusive prefix of cGt
  int posT = nGt + offEq + sEq - cEq;    // tie slots after all strict-greater

  // collect selected entries (fixed order -> deterministic)
#pragma unroll
  for (int c = 0; c < 4; c++) {
    unsigned int rr[4] = {raw[c].x, raw[c].y, raw[c].z, raw[c].w};
#pragma unroll
    for (int e = 0; e < 8; e++) {
      unsigned int u16 = (e & 1) ? (rr[e >> 1] >> 16) : (rr[e >> 1] & 0xFFFFu);
      unsigned int k = hkey(u16);
      if (k > K || (k == K && posT < TOPK)) {
        int p = c * 2048 + tid * 8 + e;   // stored position == column (natural)
        int slot = (k > K) ? posG : posT;
        selCol[slot] = p;
        selSc[slot] = h2f((unsigned short)u16);
      }
      if (k > K) posG++;
      else if (k == K) posT++;
    }
  }
  __syncthreads();

  // softmax over the 32 selected (wave-parallel, deterministic), compact out
  if (tid < TOPK) {
    float s = selSc[tid];
    float m = s;
#pragma unroll
    for (int off = 16; off >= 1; off >>= 1) m = fmaxf(m, __shfl_xor(m, off, 64));
    float e = __expf(s - m);
    float Z = e;
#pragma unroll
    for (int off = 16; off >= 1; off >>= 1) Z += __shfl_xor(Z, off, 64);
    selC[(size_t)row * TOPK + tid] = selCol[tid];
    selWt[(size_t)row * TOPK + tid] = e / Z;
  }
}

// ---------------------------------------------------------------------------
// Kernel 3b: streaming dense-weights fill (register float4 zeros + scatter
// after barrier) + fused gather (fully unrolled: 32 independent loads in
// flight). One block per row. fb written in TILE layout for gate.
// ---------------------------------------------------------------------------
__global__ __launch_bounds__(256) void fill_gather_kernel(
    const int* __restrict__ selC, const float* __restrict__ selWt,
    float* __restrict__ weights, const float* __restrict__ v,
    float* __restrict__ fused, unsigned short* __restrict__ fb) {
  __shared__ int sc[TOPK];
  __shared__ float sw[TOPK];
  int tid = threadIdx.x;
  int row = blockIdx.x;
  if (tid < TOPK) {
    sc[tid] = selC[(size_t)row * TOPK + tid];
    sw[tid] = selWt[(size_t)row * TOPK + tid];
  }

  // zero the dense row straight from registers (overwrites the fp16 scores,
  // which topk_kernel has already consumed)
  float* wrow = weights + (size_t)row * NN;
  float4 z4 = {0.0f, 0.0f, 0.0f, 0.0f};
#pragma unroll
  for (int c = 0; c < 8; c++) *(float4*)(wrow + c * 1024 + tid * 4) = z4;
  __syncthreads();   // zeros drained (vmcnt(0) before barrier) + sc/sw visible
  if (tid < TOPK) wrow[sc[tid]] = sw[tid];

  // fused[row][tid] = sum_i w_i * v[col_i][tid]; full unroll -> loads overlap
  float acc = 0.0f;
#pragma unroll
  for (int i = 0; i < TOPK; i++)
    acc += sw[i] * v[(size_t)sc[i] * DD + tid];
  fused[(size_t)row * DD + tid] = acc;
  fb[tile_off(row, tid)] = f2bf(acc);
}

// ---------------------------------------------------------------------------
// Kernel 4: gate = sigmoid([x|fused] @ Wg.T + bg); out = g*x + (1-g)*fused.
// bf16 MFMA, K=512 (xb then fb, both tiled). grid (16, 64). ALL fragment
// loads contiguous lane-linear.
// ---------------------------------------------------------------------------
__global__ __launch_bounds__(256) void gate_kernel(
    const unsigned short* __restrict__ xb, const unsigned short* __restrict__ fb,
    const unsigned short* __restrict__ wgb, const float* __restrict__ bg,
    const float* __restrict__ x, const float* __restrict__ fused,
    float* __restrict__ out) {
  int tid = threadIdx.x;
  int w = tid >> 6, lane = tid & 63;
  int quad = lane >> 4, l16 = lane & 15;
  int rb = blockIdx.y * 128;
  int cs = blockIdx.x * 16;
  const unsigned short* wgt = wgb + (size_t)(cs >> 4) * 8192;

  floatx4 acc[2];
  acc[0] = (floatx4){0.f, 0.f, 0.f, 0.f};
  acc[1] = (floatx4){0.f, 0.f, 0.f, 0.f};

#pragma unroll 1
  for (int kc = 0; kc < 2; kc++) {
    const unsigned short* asrc = kc ? fb : xb;
    short8v afrag[2][8];
#pragma unroll
    for (int rh = 0; rh < 2; rh++) {
      int gA = (rb + w * 32 + rh * 16) >> 4;
#pragma unroll
      for (int kbi = 0; kbi < 8; kbi++)
        afrag[rh][kbi] = *(const short8v*)(asrc + (size_t)gA * 4096 +
                                           kbi * 512 + (size_t)lane * 8);
    }
#pragma unroll
    for (int kbi = 0; kbi < 8; kbi++) {
      short8v b = *(const short8v*)(wgt + (size_t)(kc * 8 + kbi) * 512 + lane * 8);
      acc[0] = __builtin_amdgcn_mfma_f32_16x16x32_bf16(afrag[0][kbi], b, acc[0], 0, 0, 0);
      acc[1] = __builtin_amdgcn_mfma_f32_16x16x32_bf16(afrag[1][kbi], b, acc[1], 0, 0, 0);
    }
  }
#pragma unroll
  for (int rh = 0; rh < 2; rh++)
#pragma unroll
    for (int r = 0; r < 4; r++) {
      int row = rb + w * 32 + rh * 16 + quad * 4 + r;
      int col = cs + l16;
      float t = acc[rh][r] + bg[col];
      float g = 1.0f / (1.0f + __expf(-t));
      size_t o = (size_t)row * 256 + col;
      out[o] = g * x[o] + (1.0f - g) * fused[o];
    }
}

// ---------------------------------------------------------------------------
extern "C" void kernel_launch(void* const* d_in, const int* in_sizes, int n_in,
                              void* d_out, int out_size, void* d_ws, size_t ws_size,
                              hipStream_t stream) {
  const float* x      = (const float*)d_in[0];
  const float* causal = (const float*)d_in[2];
  const float* Wq = (const float*)d_in[3];
  const float* bq = (const float*)d_in[4];
  const float* Wk = (const float*)d_in[5];
  const float* bk = (const float*)d_in[6];
  const float* Wv = (const float*)d_in[7];
  const float* bv = (const float*)d_in[8];
  const float* Wg = (const float*)d_in[9];
  const float* bg = (const float*)d_in[10];

  float* out = (float*)d_out;
  float* weights = out + (size_t)NN * DD;  // fp16 score scratch lives in row head

  char* ws = (char*)d_ws;
  unsigned short* xb    = (unsigned short*)(ws);                    // 4 MB (tiled)
  unsigned short* wqkvb = (unsigned short*)(ws + (4u << 20));       // 384 KB (tiled)
  unsigned short* wgb   = (unsigned short*)(ws + (4u << 20) + (512u << 10)); // 256 KB (tiled)
  unsigned short* qb    = (unsigned short*)(ws + (5u << 20));       // 4 MB (tiled)
  unsigned short* kb    = (unsigned short*)(ws + (9u << 20));       // 4 MB (tiled, col-paired)
  float* v     = (float*)(ws + (13u << 20));                        // 8 MB
  float* fused = (float*)(ws + (21u << 20));                        // 8 MB
  unsigned short* fb = (unsigned short*)(ws + (29u << 20));         // 4 MB (tiled)
  // q/k are dead after score_kernel -> reuse their space for compact top-k
  int*   selC  = (int*)(ws + (5u << 20));                           // 1 MB
  float* selWt = (float*)(ws + (9u << 20));                         // 1 MB

  conv_kernel<<<dim3(2368), 256, 0, stream>>>(x, Wq, Wk, Wv, Wg, xb, wqkvb, wgb);
  qkv_kernel<<<dim3(6, 64, 4), 256, 0, stream>>>(xb, wqkvb, bq, bk, bv, qb, kb, v);
  score_kernel<<<dim3(SSTRIP, 64), 256, 0, stream>>>(qb, kb, causal, weights);
  topk_kernel<<<dim3(NN), 256, 0, stream>>>(weights, selC, selWt);
  fill_gather_kernel<<<dim3(NN), 256, 0, stream>>>(selC, selWt, weights, v, fused, fb);
  gate_kernel<<<dim3(16, 64), 256, 0, stream>>>(xb, fb, wgb, bg, x, fused, out);
}

// Round 12
// 811.342 us; speedup vs baseline: 1.1396x; 1.0221x over previous
//
#include <hip/hip_runtime.h>

#define NN 8192
#define DD 256
#define TOPK 32
#define SSTRIP 32   // score kernel: column strips
#define SW 256      // cols per strip
#define NIT (SW / 32)

typedef __attribute__((ext_vector_type(8))) short short8v;
typedef __attribute__((ext_vector_type(4))) float floatx4;

__device__ __forceinline__ unsigned short f2bf(float f) {
  union { float f; unsigned int u; } x;
  x.f = f;
  unsigned int r = x.u + 0x7FFFu + ((x.u >> 16) & 1u);
  return (unsigned short)(r >> 16);
}
__device__ __forceinline__ unsigned short f2h(float f) {
  _Float16 h = (_Float16)f;
  return __builtin_bit_cast(unsigned short, h);
}
__device__ __forceinline__ float h2f(unsigned short u) {
  return (float)__builtin_bit_cast(_Float16, u);
}
// monotone 16-bit key for fp16: a<b (fp16) <=> key(a)<key(b) (uint16)
__device__ __forceinline__ unsigned int hkey(unsigned int u) {
  return (u & 0x8000u) ? ((~u) & 0xFFFFu) : (u | 0x8000u);
}
// LANE-LINEAR fragment tile layout for MFMA operands (K=256 panels):
// 16-row x 256-k panel = 4096 shorts, stored [kbi][quad][l16][8].
// A wave's fragment load (lane = quad*16+l16) is lane*16B CONTIGUOUS.
__device__ __forceinline__ size_t tile_off(int row, int j) {
  return ((size_t)(row >> 4) * 4096) + (size_t)(((j >> 5) * 512) +
         (((j >> 3) & 3) * 128) + ((row & 15) * 8) + (j & 7));
}
// same, K=512 panels (for Wg): 16 x 512 = 8192 shorts
__device__ __forceinline__ size_t tile_off512(int row, int j) {
  return ((size_t)(row >> 4) * 8192) + (size_t)(((j >> 5) * 512) +
         (((j >> 3) & 3) * 128) + ((row & 15) * 8) + (j & 7));
}

// async global->LDS copy, 16B per lane, wave-uniform LDS base
#define ASYNC_CP16(gsrc, ldst)                                              \
  __builtin_amdgcn_global_load_lds(                                         \
      (__attribute__((address_space(1))) const void*)(gsrc),                \
      (__attribute__((address_space(3))) void*)(ldst), 16, 0, 0)

// ---------------------------------------------------------------------------
// Kernel 0: bf16 conversions into LANE-LINEAR TILES. xb/wqkvb tiled K=256,
// wgb tiled K=512. One float4 group per thread.
// ---------------------------------------------------------------------------
__global__ __launch_bounds__(256) void conv_kernel(
    const float* __restrict__ x,
    const float* __restrict__ Wq, const float* __restrict__ Wk,
    const float* __restrict__ Wv, const float* __restrict__ Wg,
    unsigned short* __restrict__ xb, unsigned short* __restrict__ wqkvb,
    unsigned short* __restrict__ wgb) {
  int g = blockIdx.x * 256 + threadIdx.x;   // float4 group id
  const float* src;
  unsigned short* dst;
  size_t t;
  if (g < 524288) {                 // x: 2097152 elems, row-major [8192][256]
    int e = g * 4;
    src = x + e;
    dst = xb;
    t = tile_off(e >> 8, e & 255);
  } else if (g < 524288 + 49152) {  // Wq|Wk|Wv: 3 x 65536, [256][256]
    int e2 = (g - 524288) * 4;
    int which = e2 >> 16;
    int off = e2 & 65535;
    src = ((which == 0) ? Wq : (which == 1) ? Wk : Wv) + off;
    dst = wqkvb + which * 65536;
    t = tile_off(off >> 8, off & 255);
  } else {                          // Wg: 131072, [256][512]
    int e3 = (g - 524288 - 49152) * 4;
    src = Wg + e3;
    dst = wgb;
    t = tile_off512(e3 >> 9, e3 & 511);
  }
  float4 f4 = *(const float4*)src;
  dst[t + 0] = f2bf(f4.x); dst[t + 1] = f2bf(f4.y);
  dst[t + 2] = f2bf(f4.z); dst[t + 3] = f2bf(f4.w);
}

// ---------------------------------------------------------------------------
// Kernel 1: q,k,v = x @ W.T + b via bf16 MFMA. q scaled by 1/16 (folded for
// scores). grid (6, 64, 4). ALL fragment loads contiguous (lane-linear tiles).
// k rows COLUMN-PAIRED (stored slot s = (t&1)*16 + (t&31)/2).
// ---------------------------------------------------------------------------
__global__ __launch_bounds__(256) void qkv_kernel(
    const unsigned short* __restrict__ xb,
    const unsigned short* __restrict__ wqkvb,
    const float* __restrict__ bq, const float* __restrict__ bk,
    const float* __restrict__ bvb,
    unsigned short* __restrict__ qb, unsigned short* __restrict__ kb,
    float* __restrict__ v) {
  int tid = threadIdx.x;
  int w = tid >> 6, lane = tid & 63;
  int quad = lane >> 4, l16 = lane & 15;
  int rb = blockIdx.y * 128;
  int cs = blockIdx.x * 128;   // 0..767 in steps of 128 (never crosses 256-bnd)
  int cb = cs + blockIdx.z * 32;
  int which = cb >> 8;
  int cbl = cb & 255;          // col within the 256-col W panel

  short8v afrag[2][8];
#pragma unroll
  for (int rh = 0; rh < 2; rh++) {
    int gA = (rb + w * 32 + rh * 16) >> 4;
#pragma unroll
    for (int kbi = 0; kbi < 8; kbi++)
      afrag[rh][kbi] = *(const short8v*)(xb + (size_t)gA * 4096 + kbi * 512 +
                                         (size_t)lane * 8);
  }

  const unsigned short* wt = wqkvb + which * 65536 + (size_t)(cbl >> 4) * 4096;
  floatx4 zero4 = {0.0f, 0.0f, 0.0f, 0.0f};
  floatx4 acc[2][2];
  acc[0][0] = zero4; acc[0][1] = zero4; acc[1][0] = zero4; acc[1][1] = zero4;
#pragma unroll
  for (int kbi = 0; kbi < 8; kbi++) {
    short8v b0 = *(const short8v*)(wt + kbi * 512 + lane * 8);
    short8v b1 = *(const short8v*)(wt + 4096 + kbi * 512 + lane * 8);
    acc[0][0] = __builtin_amdgcn_mfma_f32_16x16x32_bf16(afrag[0][kbi], b0, acc[0][0], 0, 0, 0);
    acc[0][1] = __builtin_amdgcn_mfma_f32_16x16x32_bf16(afrag[0][kbi], b1, acc[0][1], 0, 0, 0);
    acc[1][0] = __builtin_amdgcn_mfma_f32_16x16x32_bf16(afrag[1][kbi], b0, acc[1][0], 0, 0, 0);
    acc[1][1] = __builtin_amdgcn_mfma_f32_16x16x32_bf16(afrag[1][kbi], b1, acc[1][1], 0, 0, 0);
  }
#pragma unroll
  for (int rh = 0; rh < 2; rh++)
#pragma unroll
    for (int ch = 0; ch < 2; ch++)
#pragma unroll
      for (int r = 0; r < 4; r++) {
        int row = rb + w * 32 + rh * 16 + quad * 4 + r;
        int col = cb + ch * 16 + l16;           // 0..767
        int j = col & 255;
        const float* bias = (which == 0) ? bq : (which == 1) ? bk : bvb;
        float val = acc[rh][ch][r] + bias[j];
        if (which == 0) {
          qb[tile_off(row, j)] = f2bf(val * 0.0625f);  // /16 folds 1/sqrt(d)
        } else if (which == 1) {
          int S = (row & ~31) | ((row & 1) << 4) | ((row & 31) >> 1);
          kb[tile_off(S, j)] = f2bf(val);
        } else {
          v[(size_t)row * 256 + j] = val;
        }
      }
}

// ---------------------------------------------------------------------------
// Kernel 2: biased scores s = q@k^T (q pre-scaled) + log(clip(causal,1e-6)),
// fp16 into the first 16KB of each 32KB weights row, natural col order.
// TRIPLE-buffered kb slabs (2-deep prefetch) + counted-vmcnt barrier (T4):
// per iter issues, in pinned order: causal(it+1) [8 dwordx2] -> stage(it+2)
// [4 global_load_lds] -> MFMA(slab it) -> score stores [8 dword].
// vmcnt queue at top of iter it (steady): newest 20 = c(it+1)+s(it+2)+st(it)
// -> s_waitcnt vmcnt(20) drains slab-(it) staging (2 iters old) + stale
// stores while keeping BOTH prefetches in flight. Iter 0: prologue queue
// afrag16,s0:4,c0:8,s1:4 -> newest 12 = c0+s1 -> vmcnt(12) waits s0.
// Raw s_barrier + sched_barrier(0) fences ds_reads (rule #18).
// ---------------------------------------------------------------------------
__global__ __launch_bounds__(256) void score_kernel(
    const unsigned short* __restrict__ qb,
    const unsigned short* __restrict__ kb,
    const float* __restrict__ causal,
    float* __restrict__ weights) {
  __shared__ unsigned short sm[3][8192];   // 3 x 16KB kb slabs
  int tid = threadIdx.x;
  int w = tid >> 6, lane = tid & 63;
  int quad = lane >> 4, l16 = lane & 15;
  int rb = blockIdx.y * 128;
  int cs = blockIdx.x * SW;

  // A fragments first (oldest in vmcnt queue; drained by iter-0's wait)
  short8v afrag[2][8];
#pragma unroll
  for (int rh = 0; rh < 2; rh++) {
    int gA = (rb + w * 32 + rh * 16) >> 4;
#pragma unroll
    for (int kbi = 0; kbi < 8; kbi++)
      afrag[rh][kbi] = *(const short8v*)(qb + (size_t)gA * 4096 + kbi * 512 +
                                         (size_t)lane * 8);
  }

  // causal row pointers for this lane's 8 output rows
  const float* crow[2][4];
#pragma unroll
  for (int rh = 0; rh < 2; rh++)
#pragma unroll
    for (int r = 0; r < 4; r++) {
      int grow = rb + w * 32 + rh * 16 + quad * 4 + r;
      crow[rh][r] = causal + (size_t)grow * NN;
    }
  __builtin_amdgcn_sched_barrier(0);

  // prologue: stage slab0 ; causal(0) ; stage slab1   (pinned order)
  {
    const unsigned short* g0 = kb + (size_t)(cs >> 4) * 4096;
#pragma unroll
    for (int c = 0; c < 4; c++) {
      int chunk = w * 4 + c;
      ASYNC_CP16(g0 + chunk * 512 + lane * 8, &sm[0][chunk * 512]);
    }
  }
  __builtin_amdgcn_sched_barrier(0);
  float2 ccur[2][4];
#pragma unroll
  for (int rh = 0; rh < 2; rh++)
#pragma unroll
    for (int r = 0; r < 4; r++)
      ccur[rh][r] = *(const float2*)(crow[rh][r] + cs + 2 * l16);
  __builtin_amdgcn_sched_barrier(0);
  {
    const unsigned short* g1 = kb + (size_t)((cs + 32) >> 4) * 4096;
#pragma unroll
    for (int c = 0; c < 4; c++) {
      int chunk = w * 4 + c;
      ASYNC_CP16(g1 + chunk * 512 + lane * 8, &sm[1][chunk * 512]);
    }
  }
  __builtin_amdgcn_sched_barrier(0);

  floatx4 zero4 = {0.0f, 0.0f, 0.0f, 0.0f};
  for (int it = 0; it < NIT; it++) {
    // slab-ready wait (see queue math above); never drains the prefetches
    if (it == 0) {
      asm volatile("s_waitcnt vmcnt(12)" ::: "memory");
    } else {
      asm volatile("s_waitcnt vmcnt(20)" ::: "memory");
    }
    __builtin_amdgcn_s_barrier();
    __builtin_amdgcn_sched_barrier(0);
    int cb = cs + it * 32;

    // causal prefetch for it+1 FIRST (oldest of this iter's vm-ops)
    float2 cnxt[2][4];
    if (it + 1 < NIT) {
#pragma unroll
      for (int rh = 0; rh < 2; rh++)
#pragma unroll
        for (int r = 0; r < 4; r++)
          cnxt[rh][r] = *(const float2*)(crow[rh][r] + cb + 32 + 2 * l16);
    }
    __builtin_amdgcn_sched_barrier(0);

    // stage slab it+2 into buffer (it+2)%3 (its readers finished last iter)
    if (it + 2 < NIT) {
      const unsigned short* gn = kb + (size_t)((cb + 64) >> 4) * 4096;
      unsigned short* smn = &sm[0][0] + (size_t)((it + 2) % 3) * 8192;
#pragma unroll
      for (int c = 0; c < 4; c++) {
        int chunk = w * 4 + c;
        ASYNC_CP16(gn + chunk * 512 + lane * 8, smn + chunk * 512);
      }
    }
    __builtin_amdgcn_sched_barrier(0);

    // compute from slab it: conflict-free lane-linear ds_read_b128
    const unsigned short* smb = &sm[0][0] + (size_t)(it % 3) * 8192;
    floatx4 acc[2][2];
    acc[0][0] = zero4; acc[0][1] = zero4; acc[1][0] = zero4; acc[1][1] = zero4;
#pragma unroll
    for (int kbi = 0; kbi < 8; kbi++) {
      short8v b0 = *(const short8v*)(smb + kbi * 512 + lane * 8);
      short8v b1 = *(const short8v*)(smb + 4096 + kbi * 512 + lane * 8);
      acc[0][0] = __builtin_amdgcn_mfma_f32_16x16x32_bf16(afrag[0][kbi], b0, acc[0][0], 0, 0, 0);
      acc[0][1] = __builtin_amdgcn_mfma_f32_16x16x32_bf16(afrag[0][kbi], b1, acc[0][1], 0, 0, 0);
      acc[1][0] = __builtin_amdgcn_mfma_f32_16x16x32_bf16(afrag[1][kbi], b0, acc[1][0], 0, 0, 0);
      acc[1][1] = __builtin_amdgcn_mfma_f32_16x16x32_bf16(afrag[1][kbi], b1, acc[1][1], 0, 0, 0);
    }

    // epilogue: ccur(it) is the OLDEST outstanding vm-op -> its wait drains
    // nothing newer. acc slot (ch,l16) = actual col cb + 2*l16 + ch.
#pragma unroll
    for (int rh = 0; rh < 2; rh++)
#pragma unroll
      for (int r = 0; r < 4; r++) {
        int grow = rb + w * 32 + rh * 16 + quad * 4 + r;
        float s0 = acc[rh][0][r] + __logf(fmaxf(ccur[rh][r].x, 1e-6f));
        float s1 = acc[rh][1][r] + __logf(fmaxf(ccur[rh][r].y, 1e-6f));
        unsigned int pk = (unsigned int)f2h(s0) | ((unsigned int)f2h(s1) << 16);
        unsigned short* sbrow = (unsigned short*)(weights + (size_t)grow * NN);
        *(unsigned int*)(sbrow + cb + l16 * 2) = pk;   // natural col order
      }
#pragma unroll
    for (int rh = 0; rh < 2; rh++)
#pragma unroll
      for (int r = 0; r < 4; r++) ccur[rh][r] = cnxt[rh][r];
  }
}

// ---------------------------------------------------------------------------
// Kernel 3a: per-row top-32 via register binary-search on fp16 keys + softmax.
// Scores are in NATURAL column order -> position == column. Writes COMPACT
// selC/selWt only. One block per row.
// ---------------------------------------------------------------------------
__global__ __launch_bounds__(256) void topk_kernel(
    const float* __restrict__ weights,
    int* __restrict__ selC, float* __restrict__ selWt) {
  __shared__ int part[72];        // binary-search partials (17 x 4)
  __shared__ int part2[8];        // scan partials
  __shared__ int selCol[TOPK];
  __shared__ float selSc[TOPK];

  int tid = threadIdx.x;
  int w = tid >> 6, lane = tid & 63;
  int row = blockIdx.x;
  const unsigned short* sb = (const unsigned short*)(weights + (size_t)row * NN);

  // load 32 fp16 scores (coalesced), build packed monotone keys
  uint4 raw[4];
#pragma unroll
  for (int c = 0; c < 4; c++)
    raw[c] = *(const uint4*)(sb + c * 2048 + tid * 8);
  unsigned int keys[16];
#pragma unroll
  for (int c = 0; c < 4; c++) {
    unsigned int rr[4] = {raw[c].x, raw[c].y, raw[c].z, raw[c].w};
#pragma unroll
    for (int u = 0; u < 4; u++) {
      unsigned int klo = hkey(rr[u] & 0xFFFFu);
      unsigned int khi = hkey(rr[u] >> 16);
      keys[c * 4 + u] = klo | (khi << 16);
    }
  }

  // binary search: smallest t with count(key > t) < TOPK  -> t = 32nd key
  int lo = 0, hi = 65535;
#pragma unroll 1
  for (int it = 0; it < 16; it++) {
    unsigned int mid = (unsigned int)((lo + hi) >> 1);
    int cnt = 0;
#pragma unroll
    for (int u = 0; u < 16; u++) {
      cnt += ((keys[u] & 0xFFFFu) > mid);
      cnt += ((keys[u] >> 16) > mid);
    }
#pragma unroll
    for (int off = 32; off >= 1; off >>= 1) cnt += __shfl_xor(cnt, off, 64);
    if (lane == 0) part[it * 4 + w] = cnt;
    __syncthreads();
    int tot = part[it * 4] + part[it * 4 + 1] + part[it * 4 + 2] + part[it * 4 + 3];
    if (lo < hi) { if (tot < TOPK) hi = (int)mid; else lo = (int)mid + 1; }
  }
  unsigned int K = (unsigned int)lo;

  // nGt = count(key > K)
  {
    int cnt = 0;
#pragma unroll
    for (int u = 0; u < 16; u++) {
      cnt += ((keys[u] & 0xFFFFu) > K);
      cnt += ((keys[u] >> 16) > K);
    }
#pragma unroll
    for (int off = 32; off >= 1; off >>= 1) cnt += __shfl_xor(cnt, off, 64);
    if (lane == 0) part[64 + w] = cnt;
  }
  __syncthreads();
  int nGt = part[64] + part[65] + part[66] + part[67];

  // per-thread counts + shuffle-based prefix scans for deterministic slots
  int cGt = 0, cEq = 0;
#pragma unroll
  for (int u = 0; u < 16; u++) {
    unsigned int a = keys[u] & 0xFFFFu, b = keys[u] >> 16;
    cGt += (a > K) + (b > K);
    cEq += (a == K) + (b == K);
  }
  int sGt = cGt;
#pragma unroll
  for (int off = 1; off < 64; off <<= 1) {
    int t = __shfl_up(sGt, off, 64);
    if (lane >= off) sGt += t;
  }
  if (lane == 63) part2[w] = sGt;
  int sEq = cEq;
#pragma unroll
  for (int off = 1; off < 64; off <<= 1) {
    int t = __shfl_up(sEq, off, 64);
    if (lane >= off) sEq += t;
  }
  if (lane == 63) part2[4 + w] = sEq;
  __syncthreads();
  int offGt = 0, offEq = 0;
  for (int j = 0; j < w; j++) { offGt += part2[j]; offEq += part2[4 + j]; }
  int posG = offGt + sGt - cGt;          // exclusive prefix of cGt
  int posT = nGt + offEq + sEq - cEq;    // tie slots after all strict-greater

  // collect selected entries (fixed order -> deterministic)
#pragma unroll
  for (int c = 0; c < 4; c++) {
    unsigned int rr[4] = {raw[c].x, raw[c].y, raw[c].z, raw[c].w};
#pragma unroll
    for (int e = 0; e < 8; e++) {
      unsigned int u16 = (e & 1) ? (rr[e >> 1] >> 16) : (rr[e >> 1] & 0xFFFFu);
      unsigned int k = hkey(u16);
      if (k > K || (k == K && posT < TOPK)) {
        int p = c * 2048 + tid * 8 + e;   // stored position == column (natural)
        int slot = (k > K) ? posG : posT;
        selCol[slot] = p;
        selSc[slot] = h2f((unsigned short)u16);
      }
      if (k > K) posG++;
      else if (k == K) posT++;
    }
  }
  __syncthreads();

  // softmax over the 32 selected (wave-parallel, deterministic), compact out
  if (tid < TOPK) {
    float s = selSc[tid];
    float m = s;
#pragma unroll
    for (int off = 16; off >= 1; off >>= 1) m = fmaxf(m, __shfl_xor(m, off, 64));
    float e = __expf(s - m);
    float Z = e;
#pragma unroll
    for (int off = 16; off >= 1; off >>= 1) Z += __shfl_xor(Z, off, 64);
    selC[(size_t)row * TOPK + tid] = selCol[tid];
    selWt[(size_t)row * TOPK + tid] = e / Z;
  }
}

// ---------------------------------------------------------------------------
// Kernel 3b: streaming dense-weights fill (register float4 zeros + scatter
// after barrier) + fused gather (fully unrolled: 32 independent loads in
// flight). One block per row. fb written in TILE layout for gate.
// ---------------------------------------------------------------------------
__global__ __launch_bounds__(256) void fill_gather_kernel(
    const int* __restrict__ selC, const float* __restrict__ selWt,
    float* __restrict__ weights, const float* __restrict__ v,
    float* __restrict__ fused, unsigned short* __restrict__ fb) {
  __shared__ int sc[TOPK];
  __shared__ float sw[TOPK];
  int tid = threadIdx.x;
  int row = blockIdx.x;
  if (tid < TOPK) {
    sc[tid] = selC[(size_t)row * TOPK + tid];
    sw[tid] = selWt[(size_t)row * TOPK + tid];
  }

  // zero the dense row straight from registers (overwrites the fp16 scores,
  // which topk_kernel has already consumed)
  float* wrow = weights + (size_t)row * NN;
  float4 z4 = {0.0f, 0.0f, 0.0f, 0.0f};
#pragma unroll
  for (int c = 0; c < 8; c++) *(float4*)(wrow + c * 1024 + tid * 4) = z4;
  __syncthreads();   // zeros drained (vmcnt(0) before barrier) + sc/sw visible
  if (tid < TOPK) wrow[sc[tid]] = sw[tid];

  // fused[row][tid] = sum_i w_i * v[col_i][tid]; full unroll -> loads overlap
  float acc = 0.0f;
#pragma unroll
  for (int i = 0; i < TOPK; i++)
    acc += sw[i] * v[(size_t)sc[i] * DD + tid];
  fused[(size_t)row * DD + tid] = acc;
  fb[tile_off(row, tid)] = f2bf(acc);
}

// ---------------------------------------------------------------------------
// Kernel 4: gate = sigmoid([x|fused] @ Wg.T + bg); out = g*x + (1-g)*fused.
// bf16 MFMA, K=512 (xb then fb, both tiled). grid (16, 64). ALL fragment
// loads contiguous lane-linear.
// ---------------------------------------------------------------------------
__global__ __launch_bounds__(256) void gate_kernel(
    const unsigned short* __restrict__ xb, const unsigned short* __restrict__ fb,
    const unsigned short* __restrict__ wgb, const float* __restrict__ bg,
    const float* __restrict__ x, const float* __restrict__ fused,
    float* __restrict__ out) {
  int tid = threadIdx.x;
  int w = tid >> 6, lane = tid & 63;
  int quad = lane >> 4, l16 = lane & 15;
  int rb = blockIdx.y * 128;
  int cs = blockIdx.x * 16;
  const unsigned short* wgt = wgb + (size_t)(cs >> 4) * 8192;

  floatx4 acc[2];
  acc[0] = (floatx4){0.f, 0.f, 0.f, 0.f};
  acc[1] = (floatx4){0.f, 0.f, 0.f, 0.f};

#pragma unroll 1
  for (int kc = 0; kc < 2; kc++) {
    const unsigned short* asrc = kc ? fb : xb;
    short8v afrag[2][8];
#pragma unroll
    for (int rh = 0; rh < 2; rh++) {
      int gA = (rb + w * 32 + rh * 16) >> 4;
#pragma unroll
      for (int kbi = 0; kbi < 8; kbi++)
        afrag[rh][kbi] = *(const short8v*)(asrc + (size_t)gA * 4096 +
                                           kbi * 512 + (size_t)lane * 8);
    }
#pragma unroll
    for (int kbi = 0; kbi < 8; kbi++) {
      short8v b = *(const short8v*)(wgt + (size_t)(kc * 8 + kbi) * 512 + lane * 8);
      acc[0] = __builtin_amdgcn_mfma_f32_16x16x32_bf16(afrag[0][kbi], b, acc[0], 0, 0, 0);
      acc[1] = __builtin_amdgcn_mfma_f32_16x16x32_bf16(afrag[1][kbi], b, acc[1], 0, 0, 0);
    }
  }
#pragma unroll
  for (int rh = 0; rh < 2; rh++)
#pragma unroll
    for (int r = 0; r < 4; r++) {
      int row = rb + w * 32 + rh * 16 + quad * 4 + r;
      int col = cs + l16;
      float t = acc[rh][r] + bg[col];
      float g = 1.0f / (1.0f + __expf(-t));
      size_t o = (size_t)row * 256 + col;
      out[o] = g * x[o] + (1.0f - g) * fused[o];
    }
}

// ---------------------------------------------------------------------------
extern "C" void kernel_launch(void* const* d_in, const int* in_sizes, int n_in,
                              void* d_out, int out_size, void* d_ws, size_t ws_size,
                              hipStream_t stream) {
  const float* x      = (const float*)d_in[0];
  const float* causal = (const float*)d_in[2];
  const float* Wq = (const float*)d_in[3];
  const float* bq = (const float*)d_in[4];
  const float* Wk = (const float*)d_in[5];
  const float* bk = (const float*)d_in[6];
  const float* Wv = (const float*)d_in[7];
  const float* bv = (const float*)d_in[8];
  const float* Wg = (const float*)d_in[9];
  const float* bg = (const float*)d_in[10];

  float* out = (float*)d_out;
  float* weights = out + (size_t)NN * DD;  // fp16 score scratch lives in row head

  char* ws = (char*)d_ws;
  unsigned short* xb    = (unsigned short*)(ws);                    // 4 MB (tiled)
  unsigned short* wqkvb = (unsigned short*)(ws + (4u << 20));       // 384 KB (tiled)
  unsigned short* wgb   = (unsigned short*)(ws + (4u << 20) + (512u << 10)); // 256 KB (tiled)
  unsigned short* qb    = (unsigned short*)(ws + (5u << 20));       // 4 MB (tiled)
  unsigned short* kb    = (unsigned short*)(ws + (9u << 20));       // 4 MB (tiled, col-paired)
  float* v     = (float*)(ws + (13u << 20));                        // 8 MB
  float* fused = (float*)(ws + (21u << 20));                        // 8 MB
  unsigned short* fb = (unsigned short*)(ws + (29u << 20));         // 4 MB (tiled)
  // q/k are dead after score_kernel -> reuse their space for compact top-k
  int*   selC  = (int*)(ws + (5u << 20));                           // 1 MB
  float* selWt = (float*)(ws + (9u << 20));                         // 1 MB

  conv_kernel<<<dim3(2368), 256, 0, stream>>>(x, Wq, Wk, Wv, Wg, xb, wqkvb, wgb);
  qkv_kernel<<<dim3(6, 64, 4), 256, 0, stream>>>(xb, wqkvb, bq, bk, bv, qb, kb, v);
  score_kernel<<<dim3(SSTRIP, 64), 256, 0, stream>>>(qb, kb, causal, weights);
  topk_kernel<<<dim3(NN), 256, 0, stream>>>(weights, selC, selWt);
  fill_gather_kernel<<<dim3(NN), 256, 0, stream>>>(selC, selWt, weights, v, fused, fb);
  gate_kernel<<<dim3(16, 64), 256, 0, stream>>>(xb, fb, wgb, bg, x, fused, out);
}